// Round 1
// baseline (2277.050 us; speedup 1.0000x reference)
//
#include <hip/hip_runtime.h>
#include <math.h>

#define BB 8
#define CC 64
#define NN 4096
#define COUT 64
#define KK 20
#define KP1 21

// ---------------- K1: kNN (top-21 smallest distances, drop self) ----------------
__global__ __launch_bounds__(256) void knn_kernel(const float* __restrict__ x,
                                                  int* __restrict__ edges) {
    const int b = blockIdx.x >> 4;     // 16 blocks per batch
    const int tile = blockIdx.x & 15;
    const int tid = threadIdx.x;
    __shared__ float xs0[NN], xs1[NN], xs2[NN], sqv[NN];   // 64 KB
    const float* xb = x + (size_t)b * CC * NN;
    for (int i = tid; i < NN; i += 256) {
        float a0 = xb[0 * NN + i];
        float a1 = xb[1 * NN + i];
        float a2 = xb[2 * NN + i];
        xs0[i] = a0; xs1[i] = a1; xs2[i] = a2;
        sqv[i] = a0 * a0 + a1 * a1 + a2 * a2;
    }
    __syncthreads();
    const int n = tile * 256 + tid;
    const float qx = xs0[n], qy = xs1[n], qz = xs2[n];
    const float sqn = sqv[n];

    float bd[KP1];
    int bi[KP1];
#pragma unroll
    for (int i = 0; i < KP1; ++i) { bd[i] = INFINITY; bi[i] = -1; }

    for (int m = 0; m < NN; ++m) {
        float dot = qx * xs0[m] + qy * xs1[m] + qz * xs2[m];
        float d = (sqn + sqv[m]) - 2.0f * dot;
        if (d < bd[KP1 - 1]) {
            // branch-free unrolled stable insertion (ascending; equal keeps earlier idx)
#pragma unroll
            for (int i = KP1 - 1; i >= 1; --i) {
                bool sh = bd[i - 1] > d;       // element i-1 shifts to i
                bool here = bd[i] > d;         // original bd[i]: insert position
                float nd = sh ? bd[i - 1] : (here ? d : bd[i]);
                int ni = sh ? bi[i - 1] : (here ? m : bi[i]);
                bd[i] = nd; bi[i] = ni;
            }
            if (bd[0] > d) { bd[0] = d; bi[0] = m; }
        }
    }

    int row = b * NN + n;
#pragma unroll
    for (int j = 0; j < KK; ++j) edges[row * KK + j] = bi[j + 1];  // drop self (rank 0)
}

// ---------------- K2: projections P1 = (W1-W2)·x_n, P2 = W2·x_n ----------------
__global__ __launch_bounds__(256) void proj_kernel(const float* __restrict__ x,
                                                   const float* __restrict__ W,
                                                   float* __restrict__ P1,
                                                   float* __restrict__ P2) {
    int g = blockIdx.x * 256 + threadIdx.x;   // [0, 32768*64)
    int row = g >> 6;
    int o = g & 63;
    int b = row >> 12;
    int n = row & 4095;
    const float* xb = x + (size_t)b * CC * NN + n;
    const float* Wr = W + o * (2 * CC);
    float p1 = 0.f, p2 = 0.f;
#pragma unroll 8
    for (int c = 0; c < CC; ++c) {
        float xv = xb[(size_t)c * NN];        // wave-uniform (broadcast)
        float w1 = Wr[c];
        float w2 = Wr[CC + c];
        p1 += (w1 - w2) * xv;
        p2 += w2 * xv;
    }
    P1[g] = p1;                                // coalesced
    P2[g] = p2;
}

// ---------------- K3a: per-block partial BN sums ----------------
__global__ __launch_bounds__(256) void stats_kernel(const float* __restrict__ P1,
                                                    const float* __restrict__ P2,
                                                    const int* __restrict__ edges,
                                                    float* __restrict__ partials) {
    int blk = blockIdx.x;          // 512 blocks, 64 rows each
    int row0 = blk * 64;
    int o = threadIdx.x & 63;
    int rq = threadIdx.x >> 6;
    int b = row0 >> 12;
    const float* P2b = P2 + (size_t)b * NN * 64;
    float s = 0.f, s2 = 0.f;
    for (int rr = rq; rr < 64; rr += 4) {
        int row = row0 + rr;
        float p1 = P1[row * 64 + o];
        const int* e = edges + row * KK;
#pragma unroll
        for (int j = 0; j < KK; ++j) {
            int ej = e[j];                      // wave-uniform
            float v = p1 + P2b[ej * 64 + o];    // coalesced 256B gather
            s += v;
            s2 += v * v;
        }
    }
    __shared__ float sh1[256], sh2[256];
    sh1[threadIdx.x] = s;
    sh2[threadIdx.x] = s2;
    __syncthreads();
    if (threadIdx.x < 64) {
        float a = sh1[threadIdx.x] + sh1[threadIdx.x + 64] + sh1[threadIdx.x + 128] + sh1[threadIdx.x + 192];
        float a2 = sh2[threadIdx.x] + sh2[threadIdx.x + 64] + sh2[threadIdx.x + 128] + sh2[threadIdx.x + 192];
        partials[blk * 128 + threadIdx.x] = a;
        partials[blk * 128 + 64 + threadIdx.x] = a2;
    }
}

// ---------------- K3b: finalize BN -> A,C consts ----------------
__global__ __launch_bounds__(128) void finalize_kernel(const float* __restrict__ partials,
                                                       const float* __restrict__ gamma,
                                                       const float* __restrict__ beta,
                                                       float* __restrict__ consts) {
    int t = threadIdx.x;   // 0..127
    float s = 0.f;
    for (int i = 0; i < 512; ++i) s += partials[i * 128 + t];
    __shared__ float sh[128];
    sh[t] = s;
    __syncthreads();
    if (t < 64) {
        float sum = sh[t];
        float sumsq = sh[64 + t];
        const float M = (float)((size_t)BB * NN * KK);  // 655360
        float mean = sum / M;
        float var = sumsq / M - mean * mean;
        float inv = 1.0f / sqrtf(var + 1e-5f);
        float A = gamma[t] * inv;
        float Cv = beta[t] - mean * A;
        consts[t] = A;
        consts[64 + t] = Cv;
    }
}

// ---------------- K4: normalize + leaky + max over k, transposed store ----------------
__global__ __launch_bounds__(256) void out_kernel(const float* __restrict__ P1,
                                                  const float* __restrict__ P2,
                                                  const int* __restrict__ edges,
                                                  const float* __restrict__ consts,
                                                  float* __restrict__ out) {
    int blk = blockIdx.x;
    int row0 = blk * 64;
    int o = threadIdx.x & 63;
    int rq = threadIdx.x >> 6;
    int b = row0 >> 12;
    int n0 = row0 & 4095;
    const float* P2b = P2 + (size_t)b * NN * 64;
    float A = consts[o];
    float Cv = consts[64 + o];
    __shared__ float tile[64][65];
    for (int rr = rq; rr < 64; rr += 4) {
        int row = row0 + rr;
        float p1 = P1[row * 64 + o];
        const int* e = edges + row * KK;
        float mx = -INFINITY;
#pragma unroll
        for (int j = 0; j < KK; ++j) {
            float h = p1 + P2b[e[j] * 64 + o];
            float hn = h * A + Cv;
            float act = hn >= 0.f ? hn : 0.2f * hn;
            mx = fmaxf(mx, act);
        }
        tile[rr][o] = mx;
    }
    __syncthreads();
    int w = threadIdx.x >> 6;
    int lane = threadIdx.x & 63;
    for (int o2 = w * 16; o2 < w * 16 + 16; ++o2) {
        out[((size_t)(b * 64 + o2)) * NN + n0 + lane] = tile[lane][o2];  // coalesced 256B
    }
}

extern "C" void kernel_launch(void* const* d_in, const int* in_sizes, int n_in,
                              void* d_out, int out_size, void* d_ws, size_t ws_size,
                              hipStream_t stream) {
    const float* x = (const float*)d_in[0];
    const float* W = (const float*)d_in[1];
    const float* gamma = (const float*)d_in[2];
    const float* beta = (const float*)d_in[3];
    float* out = (float*)d_out;

    char* w = (char*)d_ws;
    int* edges = (int*)w;                                        // 8*4096*20*4 = 2,621,440 B
    float* P1 = (float*)(w + (size_t)BB * NN * KK * 4);
    float* P2 = P1 + (size_t)BB * NN * 64;                       // 8.4 MB each
    float* partials = P2 + (size_t)BB * NN * 64;                 // 512*128 floats
    float* consts = partials + 512 * 128;                        // 128 floats

    knn_kernel<<<128, 256, 0, stream>>>(x, edges);
    proj_kernel<<<8192, 256, 0, stream>>>(x, W, P1, P2);
    stats_kernel<<<512, 256, 0, stream>>>(P1, P2, edges, partials);
    finalize_kernel<<<1, 128, 0, stream>>>(partials, gamma, beta, consts);
    out_kernel<<<512, 256, 0, stream>>>(P1, P2, edges, consts, out);
}

// Round 4
// 1378.891 us; speedup vs baseline: 1.6514x; 1.6514x over previous
//
#include <hip/hip_runtime.h>
#include <math.h>

#define BB 8
#define CC 64
#define NN 4096
#define COUT 64
#define KK 20
#define CHUNK 2048

// NumPy-exact (FMA-free, left-to-right) distance pieces. np.einsum / np.sum
// round every mul and add individually; __f*_rn intrinsics forbid contraction.
__device__ __forceinline__ float np_sq(float ax, float ay, float az) {
    return __fadd_rn(__fadd_rn(__fmul_rn(ax, ax), __fmul_rn(ay, ay)), __fmul_rn(az, az));
}
__device__ __forceinline__ float np_dist(float qx, float qy, float qz, float sqn, float4 p) {
    float dot = __fadd_rn(__fadd_rn(__fmul_rn(qx, p.x), __fmul_rn(qy, p.y)), __fmul_rn(qz, p.z));
    return __fsub_rn(__fadd_rn(sqn, p.w), __fmul_rn(2.0f, dot));
}

// ---------------- K1a: per-chunk top-20 distances (no indices, self skipped) ----------------
__global__ __launch_bounds__(64) void knn_part(const float* __restrict__ x,
                                               float* __restrict__ pd) {
    const int g = blockIdx.x;          // [0,1024)
    const int h = g & 1;               // candidate half
    const int w = g >> 1;              // query wave [0,512)
    const int b = w >> 6;
    const int lane = threadIdx.x;
    const int n = (w & 63) * 64 + lane;
    const float* xb = x + (size_t)b * CC * NN;

    __shared__ float4 pts[CHUNK + 1];  // 32784 B
    for (int i = lane; i < CHUNK; i += 64) {
        int m = h * CHUNK + i;
        float ax = xb[0 * NN + m], ay = xb[NN + m], az = xb[2 * NN + m];
        pts[i] = make_float4(ax, ay, az, np_sq(ax, ay, az));
    }
    if (lane == 0) pts[CHUNK] = make_float4(0.f, 0.f, 0.f, 0.f);  // prefetch pad
    __syncthreads();

    const float qx = xb[n], qy = xb[NN + n], qz = xb[2 * NN + n];
    const float sqn = np_sq(qx, qy, qz);
    const int self = n - h * CHUNK;    // outside [0,CHUNK) -> never matches

    float bd[KK];
#pragma unroll
    for (int i = 0; i < KK; ++i) bd[i] = INFINITY;

    float4 cur = pts[0];
    for (int i = 0; i < CHUNK; ++i) {
        float4 nxt = pts[i + 1];                    // prefetch (pad slot at end)
        float d = np_dist(qx, qy, qz, sqn, cur);
        if (i == self) d = INFINITY;
        if (d < bd[KK - 1]) {
            // distance-only sorted insert: 3 ops/slot
#pragma unroll
            for (int s = KK - 1; s >= 1; --s) {
                bd[s] = (bd[s - 1] > d) ? bd[s - 1] : ((bd[s] > d) ? d : bd[s]);
            }
            if (bd[0] > d) bd[0] = d;
        }
        cur = nxt;
    }

    int q = w * 64 + lane;             // global query id [0,32768)
    float* outp = pd + (size_t)q * (2 * KK) + h * KK;
#pragma unroll
    for (int j = 0; j < KK; ++j) outp[j] = bd[j];
}

// ---------------- K1b: tau = 20th smallest of union; tie-correct two-phase collect ----------------
__global__ __launch_bounds__(256) void knn_final(const float* __restrict__ x,
                                                 const float* __restrict__ pd,
                                                 int* __restrict__ edges) {
    const int blk = blockIdx.x;        // 128
    const int b = blk >> 4;
    const int n = (blk & 15) * 256 + threadIdx.x;
    const int q = b * NN + n;
    const float* xb = x + (size_t)b * CC * NN;

    __shared__ float4 pts[NN];         // 65536 B
    for (int i = threadIdx.x; i < NN; i += 256) {
        float ax = xb[i], ay = xb[NN + i], az = xb[2 * NN + i];
        pts[i] = make_float4(ax, ay, az, np_sq(ax, ay, az));
    }
    __syncthreads();

    const float qx = xb[n], qy = xb[NN + n], qz = xb[2 * NN + n];
    const float sqn = np_sq(qx, qy, qz);

    float a[KK], c[KK];
    const float* pq = pd + (size_t)q * (2 * KK);
#pragma unroll
    for (int j = 0; j < KK; ++j) { a[j] = pq[j]; c[j] = pq[KK + j]; }

    // tau = KK-th smallest of (a ∪ c): min over s of max(a[s-1], c[KK-1-s]); static unroll
    float tau = INFINITY;
#pragma unroll
    for (int s = 0; s <= KK; ++s) {
        float av = (s > 0) ? a[s - 1] : -INFINITY;
        float cv = (s < KK) ? c[KK - 1 - s] : -INFINITY;
        tau = fminf(tau, fmaxf(av, cv));
    }

    int cnt = 0;
    int* erow = edges + (size_t)q * KK;

    // Pass A: all strictly-below-tau neighbors (at most 19 by definition of tau)
    float4 cur = pts[0];
    for (int m = 0; m < NN; ++m) {
        float4 nxt = pts[(m + 1) & (NN - 1)];
        float d = np_dist(qx, qy, qz, sqn, cur);
        if (m != n && d < tau && cnt < KK) {
            erow[cnt] = m;
            cnt++;
        }
        cur = nxt;
    }
    // Pass B: fill remaining slots with d == tau ties, ascending index (stable top_k)
    cur = pts[0];
    for (int m = 0; m < NN; ++m) {
        float4 nxt = pts[(m + 1) & (NN - 1)];
        float d = np_dist(qx, qy, qz, sqn, cur);
        if (m != n && d == tau && cnt < KK) {
            erow[cnt] = m;
            cnt++;
        }
        cur = nxt;
    }
    // Guard (theoretically unreachable): never leave stale workspace in edges
    for (int j = cnt; j < KK; ++j) erow[j] = (n + 1 + j) & (NN - 1);
}

// ---------------- K2: projections P1 = (W1-W2)·x_n, P2 = W2·x_n ----------------
__global__ __launch_bounds__(256) void proj_kernel(const float* __restrict__ x,
                                                   const float* __restrict__ W,
                                                   float* __restrict__ P1,
                                                   float* __restrict__ P2) {
    int g = blockIdx.x * 256 + threadIdx.x;   // [0, 32768*64)
    int row = g >> 6;
    int o = g & 63;
    int b = row >> 12;
    int n = row & 4095;
    const float* xb = x + (size_t)b * CC * NN + n;
    const float* Wr = W + o * (2 * CC);
    float p1 = 0.f, p2 = 0.f;
#pragma unroll 8
    for (int c = 0; c < CC; ++c) {
        float xv = xb[(size_t)c * NN];        // wave-uniform (broadcast)
        float w1 = Wr[c];
        float w2 = Wr[CC + c];
        p1 += (w1 - w2) * xv;
        p2 += w2 * xv;
    }
    P1[g] = p1;                                // coalesced
    P2[g] = p2;
}

// ---------------- K3a: per-block partial BN sums ----------------
__global__ __launch_bounds__(256) void stats_kernel(const float* __restrict__ P1,
                                                    const float* __restrict__ P2,
                                                    const int* __restrict__ edges,
                                                    float* __restrict__ partials) {
    int blk = blockIdx.x;          // 512 blocks, 64 rows each
    int row0 = blk * 64;
    int o = threadIdx.x & 63;
    int rq = threadIdx.x >> 6;
    int b = row0 >> 12;
    const float* P2b = P2 + (size_t)b * NN * 64;
    float s = 0.f, s2 = 0.f;
    for (int rr = rq; rr < 64; rr += 4) {
        int row = row0 + rr;
        float p1 = P1[row * 64 + o];
        const int* e = edges + row * KK;
#pragma unroll
        for (int j = 0; j < KK; ++j) {
            int ej = e[j];                      // wave-uniform
            float v = p1 + P2b[ej * 64 + o];    // coalesced 256B gather
            s += v;
            s2 += v * v;
        }
    }
    __shared__ float sh1[256], sh2[256];
    sh1[threadIdx.x] = s;
    sh2[threadIdx.x] = s2;
    __syncthreads();
    if (threadIdx.x < 64) {
        float a = sh1[threadIdx.x] + sh1[threadIdx.x + 64] + sh1[threadIdx.x + 128] + sh1[threadIdx.x + 192];
        float a2 = sh2[threadIdx.x] + sh2[threadIdx.x + 64] + sh2[threadIdx.x + 128] + sh2[threadIdx.x + 192];
        partials[blk * 128 + threadIdx.x] = a;
        partials[blk * 128 + 64 + threadIdx.x] = a2;
    }
}

// ---------------- K3b: finalize BN -> A,C consts ----------------
__global__ __launch_bounds__(128) void finalize_kernel(const float* __restrict__ partials,
                                                       const float* __restrict__ gamma,
                                                       const float* __restrict__ beta,
                                                       float* __restrict__ consts) {
    int t = threadIdx.x;   // 0..127
    float s = 0.f;
    for (int i = 0; i < 512; ++i) s += partials[i * 128 + t];
    __shared__ float sh[128];
    sh[t] = s;
    __syncthreads();
    if (t < 64) {
        float sum = sh[t];
        float sumsq = sh[64 + t];
        const float M = (float)((size_t)BB * NN * KK);  // 655360
        float mean = sum / M;
        float var = sumsq / M - mean * mean;
        float inv = 1.0f / sqrtf(var + 1e-5f);
        float A = gamma[t] * inv;
        float Cv = beta[t] - mean * A;
        consts[t] = A;
        consts[64 + t] = Cv;
    }
}

// ---------------- K4: normalize + leaky + max over k, transposed store ----------------
__global__ __launch_bounds__(256) void out_kernel(const float* __restrict__ P1,
                                                  const float* __restrict__ P2,
                                                  const int* __restrict__ edges,
                                                  const float* __restrict__ consts,
                                                  float* __restrict__ out) {
    int blk = blockIdx.x;
    int row0 = blk * 64;
    int o = threadIdx.x & 63;
    int rq = threadIdx.x >> 6;
    int b = row0 >> 12;
    int n0 = row0 & 4095;
    const float* P2b = P2 + (size_t)b * NN * 64;
    float A = consts[o];
    float Cv = consts[64 + o];
    __shared__ float tile[64][65];
    for (int rr = rq; rr < 64; rr += 4) {
        int row = row0 + rr;
        float p1 = P1[row * 64 + o];
        const int* e = edges + row * KK;
        float mx = -INFINITY;
#pragma unroll
        for (int j = 0; j < KK; ++j) {
            float h = p1 + P2b[e[j] * 64 + o];
            float hn = h * A + Cv;
            float act = hn >= 0.f ? hn : 0.2f * hn;
            mx = fmaxf(mx, act);
        }
        tile[rr][o] = mx;
    }
    __syncthreads();
    int w = threadIdx.x >> 6;
    int lane = threadIdx.x & 63;
    for (int o2 = w * 16; o2 < w * 16 + 16; ++o2) {
        out[((size_t)(b * 64 + o2)) * NN + n0 + lane] = tile[lane][o2];  // coalesced 256B
    }
}

extern "C" void kernel_launch(void* const* d_in, const int* in_sizes, int n_in,
                              void* d_out, int out_size, void* d_ws, size_t ws_size,
                              hipStream_t stream) {
    const float* x = (const float*)d_in[0];
    const float* W = (const float*)d_in[1];
    const float* gamma = (const float*)d_in[2];
    const float* beta = (const float*)d_in[3];
    float* out = (float*)d_out;

    char* w = (char*)d_ws;
    int* edges = (int*)w;                                        // 2,621,440 B
    float* P1 = (float*)(w + (size_t)BB * NN * KK * 4);          // 8.39 MB
    float* P2 = P1 + (size_t)BB * NN * 64;                       // 8.39 MB
    float* partials = P2 + (size_t)BB * NN * 64;                 // 512*128 floats
    float* consts = partials + 512 * 128;                        // 128 floats
    // pd (partial distances, 32768*40 floats = 5.24 MB) aliases P1's region:
    // dead before proj_kernel writes P1 (stream-ordered).
    float* pd = P1;

    knn_part<<<1024, 64, 0, stream>>>(x, pd);
    knn_final<<<128, 256, 0, stream>>>(x, pd, edges);
    proj_kernel<<<8192, 256, 0, stream>>>(x, W, P1, P2);
    stats_kernel<<<512, 256, 0, stream>>>(P1, P2, edges, partials);
    finalize_kernel<<<1, 128, 0, stream>>>(partials, gamma, beta, consts);
    out_kernel<<<512, 256, 0, stream>>>(P1, P2, edges, consts, out);
}

// Round 5
// 783.713 us; speedup vs baseline: 2.9055x; 1.7594x over previous
//
#include <hip/hip_runtime.h>
#include <math.h>

#define BB 8
#define CC 64
#define NN 4096
#define COUT 64
#define KK 20
#define NCH 4
#define CHUNK 1024
#define NQ 32768

// NumPy-exact (FMA-free, left-to-right) distance pieces. np.einsum / np.sum
// round every mul and add individually; __f*_rn intrinsics forbid contraction.
__device__ __forceinline__ float np_sq(float ax, float ay, float az) {
    return __fadd_rn(__fadd_rn(__fmul_rn(ax, ax), __fmul_rn(ay, ay)), __fmul_rn(az, az));
}
__device__ __forceinline__ float np_dist(float qx, float qy, float qz, float sqn, float4 p) {
    float dot = __fadd_rn(__fadd_rn(__fmul_rn(qx, p.x), __fmul_rn(qy, p.y)), __fmul_rn(qz, p.z));
    return __fsub_rn(__fadd_rn(sqn, p.w), __fmul_rn(2.0f, dot));
}

// ---------------- K1a: per-chunk top-20 distances, branchless bubble insert ----------------
// grid: 128 query-groups x 4 chunks = 512 blocks x 256 threads (2 waves/SIMD machine-wide)
__global__ __launch_bounds__(256) void knn_part(const float* __restrict__ x,
                                                float* __restrict__ pd) {
    const int grp = blockIdx.x >> 2;
    const int ch = blockIdx.x & 3;
    const int tid = threadIdx.x;
    const int q = grp * 256 + tid;
    const int b = q >> 12;
    const int n = q & (NN - 1);
    const float* xb = x + (size_t)b * CC * NN;

    __shared__ float4 pts[CHUNK];      // 16 KB
    for (int i = tid; i < CHUNK; i += 256) {
        int m = ch * CHUNK + i;
        float ax = xb[m], ay = xb[NN + m], az = xb[2 * NN + m];
        pts[i] = make_float4(ax, ay, az, np_sq(ax, ay, az));
    }
    __syncthreads();

    const float qx = xb[n], qy = xb[NN + n], qz = xb[2 * NN + n];
    const float sqn = np_sq(qx, qy, qz);
    const int self_local = ((n >> 10) == ch) ? (n & (CHUNK - 1)) : -1;

    float bd[KK];
#pragma unroll
    for (int i = 0; i < KK; ++i) bd[i] = INFINITY;

#pragma unroll 2
    for (int i = 0; i < CHUNK; ++i) {
        float4 p = pts[i];                       // wave-uniform -> LDS broadcast
        float d = np_dist(qx, qy, qz, sqn, p);
        d = (i == self_local) ? INFINITY : d;
        // branchless sorted insert: bd stays ascending; largest bubbles out
#pragma unroll
        for (int s = 0; s < KK; ++s) {
            float lo = fminf(bd[s], d);
            float hi = fmaxf(bd[s], d);
            bd[s] = lo;
            d = hi;
        }
    }

    // pd layout [chunk][j][q] -> coalesced stores (lanes = consecutive q)
#pragma unroll
    for (int j = 0; j < KK; ++j) pd[(size_t)(ch * KK + j) * NQ + q] = bd[j];
}

// ---------------- K1b: exact tau from 4 sorted lists + single-pass tie-budget collect ----------------
// grid: 512 blocks x 64 threads (all CUs busy)
__global__ __launch_bounds__(64) void knn_collect(const float* __restrict__ x,
                                                  const float* __restrict__ pd,
                                                  int* __restrict__ edges) {
    const int q = blockIdx.x * 64 + threadIdx.x;
    const int b = q >> 12;
    const int n = q & (NN - 1);
    const float* xb = x + (size_t)b * CC * NN;

    __shared__ float4 pts[NN];         // 64 KB
    for (int i = threadIdx.x; i < NN; i += 64) {
        float ax = xb[i], ay = xb[NN + i], az = xb[2 * NN + i];
        pts[i] = make_float4(ax, ay, az, np_sq(ax, ay, az));
    }
    __syncthreads();

    const float qx = xb[n], qy = xb[NN + n], qz = xb[2 * NN + n];
    const float sqn = np_sq(qx, qy, qz);

    float L[NCH][KK];
#pragma unroll
    for (int c = 0; c < NCH; ++c)
#pragma unroll
        for (int j = 0; j < KK; ++j) L[c][j] = pd[(size_t)(c * KK + j) * NQ + q];  // coalesced

    // A[r-1] = r-th smallest of L0 u L1 ; Bv likewise for L2 u L3 (static unrolled)
    float A[KK], Bv[KK];
#pragma unroll
    for (int r = 1; r <= KK; ++r) {
        float bestA = INFINITY, bestB = INFINITY;
#pragma unroll
        for (int j = 0; j <= KK; ++j) {
            if (j <= r) {
                float a0 = (j >= 1) ? L[0][j - 1] : -INFINITY;
                float a1 = (r - j >= 1) ? L[1][r - j - 1] : -INFINITY;
                bestA = fminf(bestA, fmaxf(a0, a1));
                float b0 = (j >= 1) ? L[2][j - 1] : -INFINITY;
                float b1 = (r - j >= 1) ? L[3][r - j - 1] : -INFINITY;
                bestB = fminf(bestB, fmaxf(b0, b1));
            }
        }
        A[r - 1] = bestA;
        Bv[r - 1] = bestB;
    }
    // tau = 20th smallest of A u Bv
    float tau = INFINITY;
#pragma unroll
    for (int s = 0; s <= KK; ++s) {
        float av = (s >= 1) ? A[s - 1] : -INFINITY;
        float bv = (KK - s >= 1) ? Bv[KK - s - 1] : -INFINITY;
        tau = fminf(tau, fmaxf(av, bv));
    }

    // exact count of d < tau over all candidates == count over the 4 lists
    int cnt_lt = 0;
#pragma unroll
    for (int c = 0; c < NCH; ++c)
#pragma unroll
        for (int j = 0; j < KK; ++j) cnt_lt += (L[c][j] < tau) ? 1 : 0;
    int budget = KK - cnt_lt;          // ties to accept, ascending index

    int cnt = 0;
    int* erow = edges + (size_t)q * KK;
#pragma unroll 2
    for (int m = 0; m < NN; ++m) {
        float4 p = pts[m];
        float d = np_dist(qx, qy, qz, sqn, p);
        if (m != n && d <= tau) {
            bool tie = !(d < tau);
            if (!tie || budget > 0) {
                if (cnt < KK) erow[cnt] = m;
                cnt++;
                if (tie) budget--;
            }
        }
    }
    for (int j = cnt; j < KK; ++j) erow[j] = (n + 1 + j) & (NN - 1);  // unreachable guard
}

// ---------------- K2: projections P1 = (W1-W2)·x_n, P2 = W2·x_n ----------------
__global__ __launch_bounds__(256) void proj_kernel(const float* __restrict__ x,
                                                   const float* __restrict__ W,
                                                   float* __restrict__ P1,
                                                   float* __restrict__ P2) {
    int g = blockIdx.x * 256 + threadIdx.x;   // [0, 32768*64)
    int row = g >> 6;
    int o = g & 63;
    int b = row >> 12;
    int n = row & 4095;
    const float* xb = x + (size_t)b * CC * NN + n;
    const float* Wr = W + o * (2 * CC);
    float p1 = 0.f, p2 = 0.f;
#pragma unroll 8
    for (int c = 0; c < CC; ++c) {
        float xv = xb[(size_t)c * NN];        // wave-uniform (broadcast)
        float w1 = Wr[c];
        float w2 = Wr[CC + c];
        p1 += (w1 - w2) * xv;
        p2 += w2 * xv;
    }
    P1[g] = p1;                                // coalesced
    P2[g] = p2;
}

// ---------------- K3a: per-block partial BN sums ----------------
__global__ __launch_bounds__(256) void stats_kernel(const float* __restrict__ P1,
                                                    const float* __restrict__ P2,
                                                    const int* __restrict__ edges,
                                                    float* __restrict__ partials) {
    int blk = blockIdx.x;          // 512 blocks, 64 rows each
    int row0 = blk * 64;
    int o = threadIdx.x & 63;
    int rq = threadIdx.x >> 6;
    int b = row0 >> 12;
    const float* P2b = P2 + (size_t)b * NN * 64;
    float s = 0.f, s2 = 0.f;
    for (int rr = rq; rr < 64; rr += 4) {
        int row = row0 + rr;
        float p1 = P1[row * 64 + o];
        const int* e = edges + row * KK;
#pragma unroll
        for (int j = 0; j < KK; ++j) {
            int ej = e[j];                      // wave-uniform
            float v = p1 + P2b[ej * 64 + o];    // coalesced 256B gather
            s += v;
            s2 += v * v;
        }
    }
    __shared__ float sh1[256], sh2[256];
    sh1[threadIdx.x] = s;
    sh2[threadIdx.x] = s2;
    __syncthreads();
    if (threadIdx.x < 64) {
        float a = sh1[threadIdx.x] + sh1[threadIdx.x + 64] + sh1[threadIdx.x + 128] + sh1[threadIdx.x + 192];
        float a2 = sh2[threadIdx.x] + sh2[threadIdx.x + 64] + sh2[threadIdx.x + 128] + sh2[threadIdx.x + 192];
        partials[blk * 128 + threadIdx.x] = a;
        partials[blk * 128 + 64 + threadIdx.x] = a2;
    }
}

// ---------------- K3b: finalize BN -> A,C consts ----------------
__global__ __launch_bounds__(128) void finalize_kernel(const float* __restrict__ partials,
                                                       const float* __restrict__ gamma,
                                                       const float* __restrict__ beta,
                                                       float* __restrict__ consts) {
    int t = threadIdx.x;   // 0..127
    float s = 0.f;
    for (int i = 0; i < 512; ++i) s += partials[i * 128 + t];
    __shared__ float sh[128];
    sh[t] = s;
    __syncthreads();
    if (t < 64) {
        float sum = sh[t];
        float sumsq = sh[64 + t];
        const float M = (float)((size_t)BB * NN * KK);  // 655360
        float mean = sum / M;
        float var = sumsq / M - mean * mean;
        float inv = 1.0f / sqrtf(var + 1e-5f);
        float A = gamma[t] * inv;
        float Cv = beta[t] - mean * A;
        consts[t] = A;
        consts[64 + t] = Cv;
    }
}

// ---------------- K4: normalize + leaky + max over k, transposed store ----------------
__global__ __launch_bounds__(256) void out_kernel(const float* __restrict__ P1,
                                                  const float* __restrict__ P2,
                                                  const int* __restrict__ edges,
                                                  const float* __restrict__ consts,
                                                  float* __restrict__ out) {
    int blk = blockIdx.x;
    int row0 = blk * 64;
    int o = threadIdx.x & 63;
    int rq = threadIdx.x >> 6;
    int b = row0 >> 12;
    int n0 = row0 & 4095;
    const float* P2b = P2 + (size_t)b * NN * 64;
    float A = consts[o];
    float Cv = consts[64 + o];
    __shared__ float tile[64][65];
    for (int rr = rq; rr < 64; rr += 4) {
        int row = row0 + rr;
        float p1 = P1[row * 64 + o];
        const int* e = edges + row * KK;
        float mx = -INFINITY;
#pragma unroll
        for (int j = 0; j < KK; ++j) {
            float h = p1 + P2b[e[j] * 64 + o];
            float hn = h * A + Cv;
            float act = hn >= 0.f ? hn : 0.2f * hn;
            mx = fmaxf(mx, act);
        }
        tile[rr][o] = mx;
    }
    __syncthreads();
    int w = threadIdx.x >> 6;
    int lane = threadIdx.x & 63;
    for (int o2 = w * 16; o2 < w * 16 + 16; ++o2) {
        out[((size_t)(b * 64 + o2)) * NN + n0 + lane] = tile[lane][o2];  // coalesced 256B
    }
}

extern "C" void kernel_launch(void* const* d_in, const int* in_sizes, int n_in,
                              void* d_out, int out_size, void* d_ws, size_t ws_size,
                              hipStream_t stream) {
    const float* x = (const float*)d_in[0];
    const float* W = (const float*)d_in[1];
    const float* gamma = (const float*)d_in[2];
    const float* beta = (const float*)d_in[3];
    float* out = (float*)d_out;

    char* w = (char*)d_ws;
    int* edges = (int*)w;                                        // 2,621,440 B
    float* P1 = (float*)(w + (size_t)BB * NN * KK * 4);          // 8.39 MB
    float* P2 = P1 + (size_t)BB * NN * 64;                       // 8.39 MB
    float* partials = P2 + (size_t)BB * NN * 64;                 // 512*128 floats
    float* consts = partials + 512 * 128;                        // 128 floats
    // pd: [4][20][32768] floats = 10.5 MB, aliases P1 + head of P2.
    // Dead before proj_kernel writes P1/P2 (stream-ordered), so safe.
    float* pd = P1;

    knn_part<<<512, 256, 0, stream>>>(x, pd);
    knn_collect<<<512, 64, 0, stream>>>(x, pd, edges);
    proj_kernel<<<8192, 256, 0, stream>>>(x, W, P1, P2);
    stats_kernel<<<512, 256, 0, stream>>>(P1, P2, edges, partials);
    finalize_kernel<<<1, 128, 0, stream>>>(partials, gamma, beta, consts);
    out_kernel<<<512, 256, 0, stream>>>(P1, P2, edges, consts, out);
}

// Round 6
// 393.187 us; speedup vs baseline: 5.7913x; 1.9932x over previous
//
#include <hip/hip_runtime.h>
#include <math.h>

#define BB 8
#define CC 64
#define NN 4096
#define COUT 64
#define KK 20
#define NCH 4
#define CHUNK 1024
#define NQ 32768

// NumPy-exact (FMA-free, left-to-right) distance pieces. np.einsum / np.sum
// round every mul and add individually; __f*_rn intrinsics forbid contraction.
__device__ __forceinline__ float np_sq(float ax, float ay, float az) {
    return __fadd_rn(__fadd_rn(__fmul_rn(ax, ax), __fmul_rn(ay, ay)), __fmul_rn(az, az));
}
__device__ __forceinline__ float np_dist(float qx, float qy, float qz, float sqn, float4 p) {
    float dot = __fadd_rn(__fadd_rn(__fmul_rn(qx, p.x), __fmul_rn(qy, p.y)), __fmul_rn(qz, p.z));
    return __fsub_rn(__fadd_rn(sqn, p.w), __fmul_rn(2.0f, dot));
}

// r-th smallest of sorted a[20] u sorted b[20], r=1..20 (static unroll, registers only)
__device__ __forceinline__ void merge20(const float* a, const float* b, float* out) {
#pragma unroll
    for (int r = 1; r <= KK; ++r) {
        float best = INFINITY;
#pragma unroll
        for (int j = 0; j <= KK; ++j) {
            if (j <= r) {
                float av = (j >= 1) ? a[j - 1] : -INFINITY;
                float bv = (r - j >= 1) ? b[r - j - 1] : -INFINITY;
                best = fminf(best, fmaxf(av, bv));
            }
        }
        out[r - 1] = best;
    }
}

// ---------------- K1a: per-chunk top-20 distances, branchless bubble insert ----------------
__global__ __launch_bounds__(256) void knn_part(const float* __restrict__ x,
                                                float* __restrict__ pd) {
    const int grp = blockIdx.x >> 2;
    const int ch = blockIdx.x & 3;
    const int tid = threadIdx.x;
    const int q = grp * 256 + tid;
    const int b = q >> 12;
    const int n = q & (NN - 1);
    const float* xb = x + (size_t)b * CC * NN;

    __shared__ float4 pts[CHUNK];      // 16 KB
    for (int i = tid; i < CHUNK; i += 256) {
        int m = ch * CHUNK + i;
        float ax = xb[m], ay = xb[NN + m], az = xb[2 * NN + m];
        pts[i] = make_float4(ax, ay, az, np_sq(ax, ay, az));
    }
    __syncthreads();

    const float qx = xb[n], qy = xb[NN + n], qz = xb[2 * NN + n];
    const float sqn = np_sq(qx, qy, qz);
    const int self_local = ((n >> 10) == ch) ? (n & (CHUNK - 1)) : -1;

    float bd[KK];
#pragma unroll
    for (int i = 0; i < KK; ++i) bd[i] = INFINITY;

#pragma unroll 2
    for (int i = 0; i < CHUNK; ++i) {
        float4 p = pts[i];                       // wave-uniform -> LDS broadcast
        float d = np_dist(qx, qy, qz, sqn, p);
        d = (i == self_local) ? INFINITY : d;
#pragma unroll
        for (int s = 0; s < KK; ++s) {
            float lo = fminf(bd[s], d);
            float hi = fmaxf(bd[s], d);
            bd[s] = lo;
            d = hi;
        }
    }

    // pd layout [chunk][j][q] -> coalesced stores
#pragma unroll
    for (int j = 0; j < KK; ++j) pd[(size_t)(ch * KK + j) * NQ + q] = bd[j];
}

// ---------------- K1b: exact tau + tie budget per query (thread-per-query) ----------------
__global__ __launch_bounds__(256) void knn_tau(const float* __restrict__ pd,
                                               float* __restrict__ taubuf,
                                               int* __restrict__ budgetbuf) {
    const int q = blockIdx.x * 256 + threadIdx.x;   // 128 blocks

    float L0[KK], L1[KK], M01[KK], M23[KK], T[KK];
#pragma unroll
    for (int j = 0; j < KK; ++j) L0[j] = pd[(size_t)(0 * KK + j) * NQ + q];
#pragma unroll
    for (int j = 0; j < KK; ++j) L1[j] = pd[(size_t)(1 * KK + j) * NQ + q];
    merge20(L0, L1, M01);
#pragma unroll
    for (int j = 0; j < KK; ++j) L0[j] = pd[(size_t)(2 * KK + j) * NQ + q];
#pragma unroll
    for (int j = 0; j < KK; ++j) L1[j] = pd[(size_t)(3 * KK + j) * NQ + q];
    merge20(L0, L1, M23);
    merge20(M01, M23, T);

    float tau = T[KK - 1];
    int cnt_lt = 0;
#pragma unroll
    for (int j = 0; j < KK; ++j) cnt_lt += (T[j] < tau) ? 1 : 0;
    taubuf[q] = tau;
    budgetbuf[q] = KK - cnt_lt;
}

// ---------------- K1c: wave-per-query lane-parallel collect (ballot + prefix) ----------------
__device__ __forceinline__ int prefix_count(unsigned long long mask) {
    int r = __builtin_amdgcn_mbcnt_lo((unsigned)mask, 0);
    return __builtin_amdgcn_mbcnt_hi((unsigned)(mask >> 32), r);
}

__global__ __launch_bounds__(256) void knn_collect(const float* __restrict__ x,
                                                   const float* __restrict__ taubuf,
                                                   const int* __restrict__ budgetbuf,
                                                   int* __restrict__ edges) {
    const int q = blockIdx.x * 4 + (threadIdx.x >> 6);   // 8192 blocks, wave-per-query
    const int lane = threadIdx.x & 63;
    const int b = q >> 12;
    const int n = q & (NN - 1);
    const float* xb = x + (size_t)b * CC * NN;

    const float qx = xb[n], qy = xb[NN + n], qz = xb[2 * NN + n];  // uniform -> broadcast
    const float sqn = np_sq(qx, qy, qz);
    const float tau = taubuf[q];
    const int budget = budgetbuf[q];

    int cnt = 0, ties = 0;
    int* erow = edges + (size_t)q * KK;

#pragma unroll 4
    for (int it = 0; it < 64; ++it) {
        int m = it * 64 + lane;
        float ax = xb[m], ay = xb[NN + m], az = xb[2 * NN + m];    // coalesced 256B
        float4 p = make_float4(ax, ay, az, np_sq(ax, ay, az));
        float d = np_dist(qx, qy, qz, sqn, p);
        bool valid = (m != n);
        bool is_lt = valid && (d < tau);
        bool is_tie = valid && (d == tau);
        unsigned long long mtie = __ballot(is_tie);
        int tie_rank = ties + prefix_count(mtie);
        bool acc = is_lt || (is_tie && tie_rank < budget);
        unsigned long long macc = __ballot(acc);
        int pos = cnt + prefix_count(macc);
        if (acc && pos < KK) erow[pos] = m;                        // in-order scatter
        cnt += __popcll(macc);
        ties += __popcll(mtie);
    }
    if (lane == 0) {
        for (int j = cnt; j < KK; ++j) erow[j] = (n + 1 + j) & (NN - 1);  // unreachable guard
    }
}

// ---------------- K2: projections P1 = (W1-W2)·x_n, P2 = W2·x_n ----------------
// wave = 64 consecutive rows (coalesced x), 4 output channels (scalar W loads)
__global__ __launch_bounds__(256) void proj_kernel(const float* __restrict__ x,
                                                   const float* __restrict__ W,
                                                   float* __restrict__ P1,
                                                   float* __restrict__ P2) {
    const int wid = blockIdx.x * 4 + (threadIdx.x >> 6);  // 8192 = 512 row-blocks x 16 o-groups
    const int lane = threadIdx.x & 63;
    const int row_block = wid >> 4;
    const int og = __builtin_amdgcn_readfirstlane(wid & 15);  // provably wave-uniform
    const int row = row_block * 64 + lane;
    const int b = row >> 12;
    const int n = row & (NN - 1);
    const float* xb = x + (size_t)b * CC * NN;

    float p1[4] = {0.f, 0.f, 0.f, 0.f};
    float p2[4] = {0.f, 0.f, 0.f, 0.f};
#pragma unroll 8
    for (int c = 0; c < CC; ++c) {
        float xv = xb[(size_t)c * NN + n];                 // coalesced 256B
#pragma unroll
        for (int j = 0; j < 4; ++j) {
            int o = og * 4 + j;
            float w1 = W[o * 2 * CC + c];                  // scalar (s_load) — uniform
            float w2 = W[o * 2 * CC + CC + c];
            p1[j] += (w1 - w2) * xv;
            p2[j] += w2 * xv;
        }
    }
#pragma unroll
    for (int j = 0; j < 4; ++j) {
        int o = og * 4 + j;
        P1[(size_t)row * 64 + o] = p1[j];
        P2[(size_t)row * 64 + o] = p2[j];
    }
}

// ---------------- K3a: per-block partial BN sums ----------------
__global__ __launch_bounds__(256) void stats_kernel(const float* __restrict__ P1,
                                                    const float* __restrict__ P2,
                                                    const int* __restrict__ edges,
                                                    float* __restrict__ partials) {
    int blk = blockIdx.x;          // 512 blocks, 64 rows each
    int row0 = blk * 64;
    int o = threadIdx.x & 63;
    int rq = threadIdx.x >> 6;
    int b = row0 >> 12;
    const float* P2b = P2 + (size_t)b * NN * 64;
    float s = 0.f, s2 = 0.f;
    for (int rr = rq; rr < 64; rr += 4) {
        int row = row0 + rr;
        float p1 = P1[row * 64 + o];
        const int* e = edges + row * KK;
#pragma unroll
        for (int j = 0; j < KK; ++j) {
            int ej = e[j];                      // wave-uniform
            float v = p1 + P2b[ej * 64 + o];    // coalesced 256B gather
            s += v;
            s2 += v * v;
        }
    }
    __shared__ float sh1[256], sh2[256];
    sh1[threadIdx.x] = s;
    sh2[threadIdx.x] = s2;
    __syncthreads();
    if (threadIdx.x < 64) {
        float a = sh1[threadIdx.x] + sh1[threadIdx.x + 64] + sh1[threadIdx.x + 128] + sh1[threadIdx.x + 192];
        float a2 = sh2[threadIdx.x] + sh2[threadIdx.x + 64] + sh2[threadIdx.x + 128] + sh2[threadIdx.x + 192];
        partials[blk * 128 + threadIdx.x] = a;
        partials[blk * 128 + 64 + threadIdx.x] = a2;
    }
}

// ---------------- K3b: finalize BN -> A,C consts ----------------
__global__ __launch_bounds__(128) void finalize_kernel(const float* __restrict__ partials,
                                                       const float* __restrict__ gamma,
                                                       const float* __restrict__ beta,
                                                       float* __restrict__ consts) {
    int t = threadIdx.x;   // 0..127
    float s = 0.f;
    for (int i = 0; i < 512; ++i) s += partials[i * 128 + t];
    __shared__ float sh[128];
    sh[t] = s;
    __syncthreads();
    if (t < 64) {
        float sum = sh[t];
        float sumsq = sh[64 + t];
        const float M = (float)((size_t)BB * NN * KK);  // 655360
        float mean = sum / M;
        float var = sumsq / M - mean * mean;
        float inv = 1.0f / sqrtf(var + 1e-5f);
        float A = gamma[t] * inv;
        float Cv = beta[t] - mean * A;
        consts[t] = A;
        consts[64 + t] = Cv;
    }
}

// ---------------- K4: normalize + leaky + max over k, transposed store ----------------
__global__ __launch_bounds__(256) void out_kernel(const float* __restrict__ P1,
                                                  const float* __restrict__ P2,
                                                  const int* __restrict__ edges,
                                                  const float* __restrict__ consts,
                                                  float* __restrict__ out) {
    int blk = blockIdx.x;
    int row0 = blk * 64;
    int o = threadIdx.x & 63;
    int rq = threadIdx.x >> 6;
    int b = row0 >> 12;
    int n0 = row0 & 4095;
    const float* P2b = P2 + (size_t)b * NN * 64;
    float A = consts[o];
    float Cv = consts[64 + o];
    __shared__ float tile[64][65];
    for (int rr = rq; rr < 64; rr += 4) {
        int row = row0 + rr;
        float p1 = P1[row * 64 + o];
        const int* e = edges + row * KK;
        float mx = -INFINITY;
#pragma unroll
        for (int j = 0; j < KK; ++j) {
            float h = p1 + P2b[e[j] * 64 + o];
            float hn = h * A + Cv;
            float act = hn >= 0.f ? hn : 0.2f * hn;
            mx = fmaxf(mx, act);
        }
        tile[rr][o] = mx;
    }
    __syncthreads();
    int w = threadIdx.x >> 6;
    int lane = threadIdx.x & 63;
    for (int o2 = w * 16; o2 < w * 16 + 16; ++o2) {
        out[((size_t)(b * 64 + o2)) * NN + n0 + lane] = tile[lane][o2];  // coalesced 256B
    }
}

extern "C" void kernel_launch(void* const* d_in, const int* in_sizes, int n_in,
                              void* d_out, int out_size, void* d_ws, size_t ws_size,
                              hipStream_t stream) {
    const float* x = (const float*)d_in[0];
    const float* W = (const float*)d_in[1];
    const float* gamma = (const float*)d_in[2];
    const float* beta = (const float*)d_in[3];
    float* out = (float*)d_out;

    char* w = (char*)d_ws;
    int* edges = (int*)w;                                        // 2,621,440 B
    float* P1 = (float*)(w + (size_t)BB * NN * KK * 4);          // 8.39 MB
    float* P2 = P1 + (size_t)BB * NN * 64;                       // 8.39 MB
    float* partials = P2 + (size_t)BB * NN * 64;                 // 512*128 floats
    float* consts = partials + 512 * 128;                        // 128 floats
    // pd [4][20][32768] (10.5 MB) + taubuf (128 KB) + budgetbuf (128 KB) alias the
    // P1/P2 region (16.8 MB): all dead before proj_kernel writes P1/P2 (stream order).
    float* pd = P1;
    float* taubuf = pd + (size_t)NCH * KK * NQ;
    int* budgetbuf = (int*)(taubuf + NQ);

    knn_part<<<512, 256, 0, stream>>>(x, pd);
    knn_tau<<<128, 256, 0, stream>>>(pd, taubuf, budgetbuf);
    knn_collect<<<8192, 256, 0, stream>>>(x, taubuf, budgetbuf, edges);
    proj_kernel<<<2048, 256, 0, stream>>>(x, W, P1, P2);
    stats_kernel<<<512, 256, 0, stream>>>(P1, P2, edges, partials);
    finalize_kernel<<<1, 128, 0, stream>>>(partials, gamma, beta, consts);
    out_kernel<<<512, 256, 0, stream>>>(P1, P2, edges, consts, out);
}

// Round 7
// 315.582 us; speedup vs baseline: 7.2154x; 1.2459x over previous
//
#include <hip/hip_runtime.h>
#include <math.h>

#define BB 8
#define CC 64
#define NN 4096
#define COUT 64
#define KK 20
#define NQ 32768

// NumPy-exact (FMA-free, left-to-right) distance pieces. np.einsum / np.sum
// round every mul and add individually; __f*_rn intrinsics forbid contraction.
__device__ __forceinline__ float np_sq(float ax, float ay, float az) {
    return __fadd_rn(__fadd_rn(__fmul_rn(ax, ax), __fmul_rn(ay, ay)), __fmul_rn(az, az));
}
__device__ __forceinline__ float np_dist(float qx, float qy, float qz, float sqn, float4 p) {
    float dot = __fadd_rn(__fadd_rn(__fmul_rn(qx, p.x), __fmul_rn(qy, p.y)), __fmul_rn(qz, p.z));
    return __fsub_rn(__fadd_rn(sqn, p.w), __fmul_rn(2.0f, dot));
}
__device__ __forceinline__ float min3f(float a, float b, float c) {
    float r; asm("v_min3_f32 %0, %1, %2, %3" : "=v"(r) : "v"(a), "v"(b), "v"(c)); return r;
}
__device__ __forceinline__ float max3f(float a, float b, float c) {
    float r; asm("v_max3_f32 %0, %1, %2, %3" : "=v"(r) : "v"(a), "v"(b), "v"(c)); return r;
}

// r-th smallest of sorted a[20] u sorted b[20], r=1..20 (static unroll, registers only)
__device__ __forceinline__ void merge20(const float* a, const float* b, float* out) {
#pragma unroll
    for (int r = 1; r <= KK; ++r) {
        float best = INFINITY;
#pragma unroll
        for (int j = 0; j <= KK; ++j) {
            if (j <= r) {
                float av = (j >= 1) ? a[j - 1] : -INFINITY;
                float bv = (r - j >= 1) ? b[r - j - 1] : -INFINITY;
                best = fminf(best, fmaxf(av, bv));
            }
        }
        out[r - 1] = best;
    }
}

// ---------------- K1a: per-chunk top-20 distances, carry-4 med3 selection network ----------------
template <int NCH>
__global__ __launch_bounds__(256) void knn_part(const float* __restrict__ x,
                                                float* __restrict__ pd) {
    constexpr int CH = NN / NCH;
    const int grp = blockIdx.x / NCH;
    const int ch = blockIdx.x % NCH;
    const int tid = threadIdx.x;
    const int q = grp * 256 + tid;
    const int b = q >> 12;
    const int n = q & (NN - 1);
    const float* xb = x + (size_t)b * CC * NN;

    __shared__ float4 pts[CH];
    for (int i = tid; i < CH; i += 256) {
        int m = ch * CH + i;
        float ax = xb[m], ay = xb[NN + m], az = xb[2 * NN + m];
        pts[i] = make_float4(ax, ay, az, np_sq(ax, ay, az));
    }
    __syncthreads();

    const float qx = xb[n], qy = xb[NN + n], qz = xb[2 * NN + n];
    const float sqn = np_sq(qx, qy, qz);
    const int self_local = ((n / CH) == ch) ? (n % CH) : -1;

    float bd[KK];
#pragma unroll
    for (int i = 0; i < KK; ++i) bd[i] = INFINITY;

#pragma unroll 2
    for (int i = 0; i < CH; i += 4) {
        float4 p0 = pts[i + 0], p1 = pts[i + 1], p2 = pts[i + 2], p3 = pts[i + 3];
        float d0 = np_dist(qx, qy, qz, sqn, p0);
        float d1 = np_dist(qx, qy, qz, sqn, p1);
        float d2 = np_dist(qx, qy, qz, sqn, p2);
        float d3 = np_dist(qx, qy, qz, sqn, p3);
        d0 = (i + 0 == self_local) ? INFINITY : d0;
        d1 = (i + 1 == self_local) ? INFINITY : d1;
        d2 = (i + 2 == self_local) ? INFINITY : d2;
        d3 = (i + 3 == self_local) ? INFINITY : d3;
        // two sorted pairs
        float a0 = fminf(d0, d1), a1 = fmaxf(d0, d1);
        float b0 = fminf(d2, d3), b1 = fmaxf(d2, d3);
        // carry-4 selection: 5 ops/slot for 4 candidates
#pragma unroll
        for (int s = 0; s < KK; ++s) {
            float mn = min3f(a0, b0, bd[s]);
            float md = __builtin_amdgcn_fmed3f(a0, b0, bd[s]);
            float mx = max3f(a0, b0, bd[s]);
            float t0 = fminf(a1, b1);
            float t1 = fmaxf(a1, b1);
            bd[s] = mn;
            a0 = md; a1 = mx;    // A' = (med3, max3), sorted
            b0 = t0; b1 = t1;    // B' = sort(old a1, old b1)
        }
    }

    // pd layout [chunk][j][q] -> coalesced stores
#pragma unroll
    for (int j = 0; j < KK; ++j) pd[(size_t)(ch * KK + j) * NQ + q] = bd[j];
}

// ---------------- K1b: exact tau + tie budget per query (thread-per-query) ----------------
template <int NCH>
__global__ __launch_bounds__(256) void knn_tau(const float* __restrict__ pd,
                                               float* __restrict__ taubuf,
                                               int* __restrict__ budgetbuf) {
    const int q = blockIdx.x * 256 + threadIdx.x;   // 128 blocks

    float T[KK], L[KK], M[KK];
#pragma unroll
    for (int j = 0; j < KK; ++j) T[j] = pd[(size_t)j * NQ + q];
#pragma unroll
    for (int c = 1; c < NCH; ++c) {
#pragma unroll
        for (int j = 0; j < KK; ++j) L[j] = pd[(size_t)(c * KK + j) * NQ + q];
        merge20(T, L, M);
#pragma unroll
        for (int j = 0; j < KK; ++j) T[j] = M[j];
    }

    float tau = T[KK - 1];
    int cnt_lt = 0;
#pragma unroll
    for (int j = 0; j < KK; ++j) cnt_lt += (T[j] < tau) ? 1 : 0;
    taubuf[q] = tau;
    budgetbuf[q] = KK - cnt_lt;
}

// ---------------- K1c: wave-per-query lane-parallel collect (ballot + prefix) ----------------
__device__ __forceinline__ int prefix_count(unsigned long long mask) {
    int r = __builtin_amdgcn_mbcnt_lo((unsigned)mask, 0);
    return __builtin_amdgcn_mbcnt_hi((unsigned)(mask >> 32), r);
}

__global__ __launch_bounds__(256) void knn_collect(const float* __restrict__ x,
                                                   const float* __restrict__ taubuf,
                                                   const int* __restrict__ budgetbuf,
                                                   int* __restrict__ edges) {
    const int q = blockIdx.x * 4 + (threadIdx.x >> 6);   // 8192 blocks, wave-per-query
    const int lane = threadIdx.x & 63;
    const int b = q >> 12;
    const int n = q & (NN - 1);
    const float* xb = x + (size_t)b * CC * NN;

    const float qx = xb[n], qy = xb[NN + n], qz = xb[2 * NN + n];  // uniform -> broadcast
    const float sqn = np_sq(qx, qy, qz);
    const float tau = taubuf[q];
    const int budget = budgetbuf[q];

    int cnt = 0, ties = 0;
    int* erow = edges + (size_t)q * KK;

#pragma unroll 4
    for (int it = 0; it < 64; ++it) {
        int m = it * 64 + lane;
        float ax = xb[m], ay = xb[NN + m], az = xb[2 * NN + m];    // coalesced 256B
        float4 p = make_float4(ax, ay, az, np_sq(ax, ay, az));
        float d = np_dist(qx, qy, qz, sqn, p);
        bool valid = (m != n);
        bool is_lt = valid && (d < tau);
        bool is_tie = valid && (d == tau);
        unsigned long long mtie = __ballot(is_tie);
        int tie_rank = ties + prefix_count(mtie);
        bool acc = is_lt || (is_tie && tie_rank < budget);
        unsigned long long macc = __ballot(acc);
        int pos = cnt + prefix_count(macc);
        if (acc && pos < KK) erow[pos] = m;                        // in-order scatter
        cnt += __popcll(macc);
        ties += __popcll(mtie);
    }
    if (lane == 0) {
        for (int j = cnt; j < KK; ++j) erow[j] = (n + 1 + j) & (NN - 1);  // unreachable guard
    }
}

// ---------------- K2: projections P1 = (W1-W2)·x_n, P2 = W2·x_n ----------------
__global__ __launch_bounds__(256) void proj_kernel(const float* __restrict__ x,
                                                   const float* __restrict__ W,
                                                   float* __restrict__ P1,
                                                   float* __restrict__ P2) {
    const int wid = blockIdx.x * 4 + (threadIdx.x >> 6);  // 8192 = 512 row-blocks x 16 o-groups
    const int lane = threadIdx.x & 63;
    const int row_block = wid >> 4;
    const int og = __builtin_amdgcn_readfirstlane(wid & 15);  // provably wave-uniform
    const int row = row_block * 64 + lane;
    const int b = row >> 12;
    const int n = row & (NN - 1);
    const float* xb = x + (size_t)b * CC * NN;

    float p1[4] = {0.f, 0.f, 0.f, 0.f};
    float p2[4] = {0.f, 0.f, 0.f, 0.f};
#pragma unroll 8
    for (int c = 0; c < CC; ++c) {
        float xv = xb[(size_t)c * NN + n];                 // coalesced 256B
#pragma unroll
        for (int j = 0; j < 4; ++j) {
            int o = og * 4 + j;
            float w1 = W[o * 2 * CC + c];                  // scalar (s_load) — uniform
            float w2 = W[o * 2 * CC + CC + c];
            p1[j] += (w1 - w2) * xv;
            p2[j] += w2 * xv;
        }
    }
#pragma unroll
    for (int j = 0; j < 4; ++j) {
        int o = og * 4 + j;
        P1[(size_t)row * 64 + o] = p1[j];
        P2[(size_t)row * 64 + o] = p2[j];
    }
}

// ---------------- K3a: per-block partial BN sums ----------------
__global__ __launch_bounds__(256) void stats_kernel(const float* __restrict__ P1,
                                                    const float* __restrict__ P2,
                                                    const int* __restrict__ edges,
                                                    float* __restrict__ partials) {
    int blk = blockIdx.x;          // 512 blocks, 64 rows each
    int row0 = blk * 64;
    int o = threadIdx.x & 63;
    int rq = threadIdx.x >> 6;
    int b = row0 >> 12;
    const float* P2b = P2 + (size_t)b * NN * 64;
    float s = 0.f, s2 = 0.f;
    for (int rr = rq; rr < 64; rr += 4) {
        int row = row0 + rr;
        float p1 = P1[row * 64 + o];
        const int* e = edges + row * KK;
#pragma unroll
        for (int j = 0; j < KK; ++j) {
            int ej = e[j];                      // wave-uniform
            float v = p1 + P2b[ej * 64 + o];    // coalesced 256B gather
            s += v;
            s2 += v * v;
        }
    }
    __shared__ float sh1[256], sh2[256];
    sh1[threadIdx.x] = s;
    sh2[threadIdx.x] = s2;
    __syncthreads();
    if (threadIdx.x < 64) {
        float a = sh1[threadIdx.x] + sh1[threadIdx.x + 64] + sh1[threadIdx.x + 128] + sh1[threadIdx.x + 192];
        float a2 = sh2[threadIdx.x] + sh2[threadIdx.x + 64] + sh2[threadIdx.x + 128] + sh2[threadIdx.x + 192];
        partials[blk * 128 + threadIdx.x] = a;
        partials[blk * 128 + 64 + threadIdx.x] = a2;
    }
}

// ---------------- K3b: finalize BN -> A,C consts ----------------
__global__ __launch_bounds__(128) void finalize_kernel(const float* __restrict__ partials,
                                                       const float* __restrict__ gamma,
                                                       const float* __restrict__ beta,
                                                       float* __restrict__ consts) {
    int t = threadIdx.x;   // 0..127
    float s = 0.f;
    for (int i = 0; i < 512; ++i) s += partials[i * 128 + t];
    __shared__ float sh[128];
    sh[t] = s;
    __syncthreads();
    if (t < 64) {
        float sum = sh[t];
        float sumsq = sh[64 + t];
        const float M = (float)((size_t)BB * NN * KK);  // 655360
        float mean = sum / M;
        float var = sumsq / M - mean * mean;
        float inv = 1.0f / sqrtf(var + 1e-5f);
        float A = gamma[t] * inv;
        float Cv = beta[t] - mean * A;
        consts[t] = A;
        consts[64 + t] = Cv;
    }
}

// ---------------- K4: normalize + leaky + max over k, transposed store ----------------
__global__ __launch_bounds__(256) void out_kernel(const float* __restrict__ P1,
                                                  const float* __restrict__ P2,
                                                  const int* __restrict__ edges,
                                                  const float* __restrict__ consts,
                                                  float* __restrict__ out) {
    int blk = blockIdx.x;
    int row0 = blk * 64;
    int o = threadIdx.x & 63;
    int rq = threadIdx.x >> 6;
    int b = row0 >> 12;
    int n0 = row0 & 4095;
    const float* P2b = P2 + (size_t)b * NN * 64;
    float A = consts[o];
    float Cv = consts[64 + o];
    __shared__ float tile[64][65];
    for (int rr = rq; rr < 64; rr += 4) {
        int row = row0 + rr;
        float p1 = P1[row * 64 + o];
        const int* e = edges + row * KK;
        float mx = -INFINITY;
#pragma unroll
        for (int j = 0; j < KK; ++j) {
            float h = p1 + P2b[e[j] * 64 + o];
            float hn = h * A + Cv;
            float act = hn >= 0.f ? hn : 0.2f * hn;
            mx = fmaxf(mx, act);
        }
        tile[rr][o] = mx;
    }
    __syncthreads();
    int w = threadIdx.x >> 6;
    int lane = threadIdx.x & 63;
    for (int o2 = w * 16; o2 < w * 16 + 16; ++o2) {
        out[((size_t)(b * 64 + o2)) * NN + n0 + lane] = tile[lane][o2];  // coalesced 256B
    }
}

extern "C" void kernel_launch(void* const* d_in, const int* in_sizes, int n_in,
                              void* d_out, int out_size, void* d_ws, size_t ws_size,
                              hipStream_t stream) {
    const float* x = (const float*)d_in[0];
    const float* W = (const float*)d_in[1];
    const float* gamma = (const float*)d_in[2];
    const float* beta = (const float*)d_in[3];
    float* out = (float*)d_out;

    char* w = (char*)d_ws;
    int* edges = (int*)w;                                        // 2,621,440 B
    float* P1 = (float*)(w + (size_t)BB * NN * KK * 4);          // 8.39 MB
    float* P2 = P1 + (size_t)BB * NN * 64;                       // 8.39 MB
    float* partials = P2 + (size_t)BB * NN * 64;                 // 512*128 floats
    float* consts = partials + 512 * 128;                        // 128 floats
    // pd [NCH][20][32768] + taubuf + budgetbuf alias the P1/P2 region: all dead
    // before proj_kernel writes P1/P2 (stream order). NCH=8 needs 21.25 MB of
    // pd+tau+budget => total ws >= 23.9 MB; fall back to NCH=4 (10.75 MB) if not.
    float* pd = P1;
    const size_t edges_bytes = (size_t)BB * NN * KK * 4;
    const size_t need8 = edges_bytes + ((size_t)8 * KK * NQ + 2 * NQ) * 4;

    if (ws_size >= need8) {
        float* taubuf = pd + (size_t)8 * KK * NQ;
        int* budgetbuf = (int*)(taubuf + NQ);
        knn_part<8><<<128 * 8, 256, 0, stream>>>(x, pd);
        knn_tau<8><<<128, 256, 0, stream>>>(pd, taubuf, budgetbuf);
        knn_collect<<<8192, 256, 0, stream>>>(x, taubuf, budgetbuf, edges);
    } else {
        float* taubuf = pd + (size_t)4 * KK * NQ;
        int* budgetbuf = (int*)(taubuf + NQ);
        knn_part<4><<<128 * 4, 256, 0, stream>>>(x, pd);
        knn_tau<4><<<128, 256, 0, stream>>>(pd, taubuf, budgetbuf);
        knn_collect<<<8192, 256, 0, stream>>>(x, taubuf, budgetbuf, edges);
    }

    proj_kernel<<<2048, 256, 0, stream>>>(x, W, P1, P2);
    stats_kernel<<<512, 256, 0, stream>>>(P1, P2, edges, partials);
    finalize_kernel<<<1, 128, 0, stream>>>(partials, gamma, beta, consts);
    out_kernel<<<512, 256, 0, stream>>>(P1, P2, edges, consts, out);
}

// Round 8
// 283.984 us; speedup vs baseline: 8.0182x; 1.1113x over previous
//
#include <hip/hip_runtime.h>
#include <math.h>

#define BB 8
#define CC 64
#define NN 4096
#define COUT 64
#define KK 20
#define NQ 32768

// NumPy-exact (FMA-free, left-to-right) distance pieces. np.einsum / np.sum
// round every mul and add individually; __f*_rn intrinsics forbid contraction.
__device__ __forceinline__ float np_sq(float ax, float ay, float az) {
    return __fadd_rn(__fadd_rn(__fmul_rn(ax, ax), __fmul_rn(ay, ay)), __fmul_rn(az, az));
}
__device__ __forceinline__ float np_dist(float qx, float qy, float qz, float sqn, float4 p) {
    float dot = __fadd_rn(__fadd_rn(__fmul_rn(qx, p.x), __fmul_rn(qy, p.y)), __fmul_rn(qz, p.z));
    return __fsub_rn(__fadd_rn(sqn, p.w), __fmul_rn(2.0f, dot));
}
// min3/max3 via minnum/maxnum chains -> compiler emits v_min3_f32 / v_max3_f32
__device__ __forceinline__ float min3f(float a, float b, float c) { return fminf(fminf(a, b), c); }
__device__ __forceinline__ float max3f(float a, float b, float c) { return fmaxf(fmaxf(a, b), c); }

// r-th smallest of sorted a[20] u sorted b[20], r=1..20 (static unroll, registers only)
__device__ __forceinline__ void merge20(const float* a, const float* b, float* out) {
#pragma unroll
    for (int r = 1; r <= KK; ++r) {
        float best = INFINITY;
#pragma unroll
        for (int j = 0; j <= KK; ++j) {
            if (j <= r) {
                float av = (j >= 1) ? a[j - 1] : -INFINITY;
                float bv = (r - j >= 1) ? b[r - j - 1] : -INFINITY;
                best = fminf(best, fmaxf(av, bv));
            }
        }
        out[r - 1] = best;
    }
}

// ---------------- K1a: per-chunk top-20 distances, carry-4 med3 selection network ----------------
template <int NCH>
__global__ __launch_bounds__(256) void knn_part(const float* __restrict__ x,
                                                float* __restrict__ pd) {
    constexpr int CH = NN / NCH;
    const int grp = blockIdx.x / NCH;
    const int ch = blockIdx.x % NCH;
    const int tid = threadIdx.x;
    const int q = grp * 256 + tid;
    const int b = q >> 12;
    const int n = q & (NN - 1);
    const float* xb = x + (size_t)b * CC * NN;

    __shared__ float4 pts[CH];
    for (int i = tid; i < CH; i += 256) {
        int m = ch * CH + i;
        float ax = xb[m], ay = xb[NN + m], az = xb[2 * NN + m];
        pts[i] = make_float4(ax, ay, az, np_sq(ax, ay, az));
    }
    __syncthreads();

    const float qx = xb[n], qy = xb[NN + n], qz = xb[2 * NN + n];
    const float sqn = np_sq(qx, qy, qz);
    const int self_local = ((n / CH) == ch) ? (n % CH) : -1;

    float bd[KK];
#pragma unroll
    for (int i = 0; i < KK; ++i) bd[i] = INFINITY;

#pragma unroll 4
    for (int i = 0; i < CH; i += 4) {
        float4 p0 = pts[i + 0], p1 = pts[i + 1], p2 = pts[i + 2], p3 = pts[i + 3];
        float d0 = np_dist(qx, qy, qz, sqn, p0);
        float d1 = np_dist(qx, qy, qz, sqn, p1);
        float d2 = np_dist(qx, qy, qz, sqn, p2);
        float d3 = np_dist(qx, qy, qz, sqn, p3);
        d0 = (i + 0 == self_local) ? INFINITY : d0;
        d1 = (i + 1 == self_local) ? INFINITY : d1;
        d2 = (i + 2 == self_local) ? INFINITY : d2;
        d3 = (i + 3 == self_local) ? INFINITY : d3;
        // two sorted pairs
        float a0 = fminf(d0, d1), a1 = fmaxf(d0, d1);
        float b0 = fminf(d2, d3), b1 = fmaxf(d2, d3);
        // carry-4 selection: 5 VALU/slot for 4 candidates (min3/med3/max3 + pair sort)
#pragma unroll
        for (int s = 0; s < KK; ++s) {
            float mn = min3f(a0, b0, bd[s]);
            float md = __builtin_amdgcn_fmed3f(a0, b0, bd[s]);
            float mx = max3f(a0, b0, bd[s]);
            float t0 = fminf(a1, b1);
            float t1 = fmaxf(a1, b1);
            bd[s] = mn;
            a0 = md; a1 = mx;    // A' = (med3, max3), sorted
            b0 = t0; b1 = t1;    // B' = sort(old a1, old b1)
        }
    }

    // pd layout [chunk][j][q] -> coalesced stores
#pragma unroll
    for (int j = 0; j < KK; ++j) pd[(size_t)(ch * KK + j) * NQ + q] = bd[j];
}

// ---------------- K1b: exact tau + tie budget per query (thread-per-query) ----------------
template <int NCH>
__global__ __launch_bounds__(256) void knn_tau(const float* __restrict__ pd,
                                               float* __restrict__ taubuf,
                                               int* __restrict__ budgetbuf) {
    const int q = blockIdx.x * 256 + threadIdx.x;   // 128 blocks

    float T[KK], L[KK], M[KK];
#pragma unroll
    for (int j = 0; j < KK; ++j) T[j] = pd[(size_t)j * NQ + q];
#pragma unroll
    for (int c = 1; c < NCH; ++c) {
#pragma unroll
        for (int j = 0; j < KK; ++j) L[j] = pd[(size_t)(c * KK + j) * NQ + q];
        merge20(T, L, M);
#pragma unroll
        for (int j = 0; j < KK; ++j) T[j] = M[j];
    }

    float tau = T[KK - 1];
    int cnt_lt = 0;
#pragma unroll
    for (int j = 0; j < KK; ++j) cnt_lt += (T[j] < tau) ? 1 : 0;
    taubuf[q] = tau;
    budgetbuf[q] = KK - cnt_lt;
}

// ---------------- K1c: wave-per-query lane-parallel collect (ballot + prefix) ----------------
__device__ __forceinline__ int prefix_count(unsigned long long mask) {
    int r = __builtin_amdgcn_mbcnt_lo((unsigned)mask, 0);
    return __builtin_amdgcn_mbcnt_hi((unsigned)(mask >> 32), r);
}

__global__ __launch_bounds__(256) void knn_collect(const float* __restrict__ x,
                                                   const float* __restrict__ taubuf,
                                                   const int* __restrict__ budgetbuf,
                                                   int* __restrict__ edges) {
    const int q = blockIdx.x * 4 + (threadIdx.x >> 6);   // 8192 blocks, wave-per-query
    const int lane = threadIdx.x & 63;
    const int b = q >> 12;
    const int n = q & (NN - 1);
    const float* xb = x + (size_t)b * CC * NN;

    const float qx = xb[n], qy = xb[NN + n], qz = xb[2 * NN + n];  // uniform -> broadcast
    const float sqn = np_sq(qx, qy, qz);
    const float tau = taubuf[q];
    const int budget = budgetbuf[q];

    int cnt = 0, ties = 0;
    int* erow = edges + (size_t)q * KK;

#pragma unroll 4
    for (int it = 0; it < 64; ++it) {
        int m = it * 64 + lane;
        float ax = xb[m], ay = xb[NN + m], az = xb[2 * NN + m];    // coalesced 256B
        float4 p = make_float4(ax, ay, az, np_sq(ax, ay, az));
        float d = np_dist(qx, qy, qz, sqn, p);
        bool valid = (m != n);
        bool is_lt = valid && (d < tau);
        bool is_tie = valid && (d == tau);
        unsigned long long mtie = __ballot(is_tie);
        int tie_rank = ties + prefix_count(mtie);
        bool acc = is_lt || (is_tie && tie_rank < budget);
        unsigned long long macc = __ballot(acc);
        int pos = cnt + prefix_count(macc);
        if (acc && pos < KK) erow[pos] = m;                        // in-order scatter
        cnt += __popcll(macc);
        ties += __popcll(mtie);
    }
    if (lane == 0) {
        for (int j = cnt; j < KK; ++j) erow[j] = (n + 1 + j) & (NN - 1);  // unreachable guard
    }
}

// ---------------- K2: projections P1 = (W1-W2)·x_n, P2 = W2·x_n ----------------
__global__ __launch_bounds__(256) void proj_kernel(const float* __restrict__ x,
                                                   const float* __restrict__ W,
                                                   float* __restrict__ P1,
                                                   float* __restrict__ P2) {
    const int wid = blockIdx.x * 4 + (threadIdx.x >> 6);  // 8192 = 512 row-blocks x 16 o-groups
    const int lane = threadIdx.x & 63;
    const int row_block = wid >> 4;
    const int og = __builtin_amdgcn_readfirstlane(wid & 15);  // provably wave-uniform
    const int row = row_block * 64 + lane;
    const int b = row >> 12;
    const int n = row & (NN - 1);
    const float* xb = x + (size_t)b * CC * NN;

    float p1[4] = {0.f, 0.f, 0.f, 0.f};
    float p2[4] = {0.f, 0.f, 0.f, 0.f};
#pragma unroll 8
    for (int c = 0; c < CC; ++c) {
        float xv = xb[(size_t)c * NN + n];                 // coalesced 256B
#pragma unroll
        for (int j = 0; j < 4; ++j) {
            int o = og * 4 + j;
            float w1 = W[o * 2 * CC + c];                  // scalar (s_load) — uniform
            float w2 = W[o * 2 * CC + CC + c];
            p1[j] += (w1 - w2) * xv;
            p2[j] += w2 * xv;
        }
    }
#pragma unroll
    for (int j = 0; j < 4; ++j) {
        int o = og * 4 + j;
        P1[(size_t)row * 64 + o] = p1[j];
        P2[(size_t)row * 64 + o] = p2[j];
    }
}

// ---------------- K3a: BN partial sums + per-row hmax -> transposed store into d_out ----------------
__global__ __launch_bounds__(256) void stats_kernel(const float* __restrict__ P1,
                                                    const float* __restrict__ P2,
                                                    const int* __restrict__ edges,
                                                    float* __restrict__ partials,
                                                    float* __restrict__ out) {
    int blk = blockIdx.x;          // 512 blocks, 64 rows each (all in one batch b)
    int row0 = blk * 64;
    int o = threadIdx.x & 63;
    int rq = threadIdx.x >> 6;
    int b = row0 >> 12;
    int n0 = row0 & (NN - 1);
    const float* P2b = P2 + (size_t)b * NN * 64;
    __shared__ float tile[64][65];
    float s = 0.f, s2 = 0.f;
    for (int rr = rq; rr < 64; rr += 4) {
        int row = row0 + rr;
        float p1 = P1[row * 64 + o];
        const int* e = edges + row * KK;
        float hm = -INFINITY;
#pragma unroll
        for (int j = 0; j < KK; ++j) {
            int ej = e[j];                      // wave-uniform
            float v = p1 + P2b[ej * 64 + o];    // coalesced 256B gather
            s += v;
            s2 += v * v;
            hm = fmaxf(hm, v);
        }
        tile[rr][o] = hm;
    }
    __shared__ float sh1[256], sh2[256];
    sh1[threadIdx.x] = s;
    sh2[threadIdx.x] = s2;
    __syncthreads();
    if (threadIdx.x < 64) {
        float a = sh1[threadIdx.x] + sh1[threadIdx.x + 64] + sh1[threadIdx.x + 128] + sh1[threadIdx.x + 192];
        float a2 = sh2[threadIdx.x] + sh2[threadIdx.x + 64] + sh2[threadIdx.x + 128] + sh2[threadIdx.x + 192];
        partials[blk * 128 + threadIdx.x] = a;
        partials[blk * 128 + 64 + threadIdx.x] = a2;
    }
    // transposed hmax store: out[b][o][n] (act applied later by out2_kernel)
    int w2 = threadIdx.x >> 6;
    int lane = threadIdx.x & 63;
    for (int o2 = w2 * 16; o2 < w2 * 16 + 16; ++o2) {
        out[((size_t)(b * 64 + o2)) * NN + n0 + lane] = tile[lane][o2];  // coalesced 256B
    }
}

// ---------------- K3b: finalize BN -> A,C consts ----------------
__global__ __launch_bounds__(128) void finalize_kernel(const float* __restrict__ partials,
                                                       const float* __restrict__ gamma,
                                                       const float* __restrict__ beta,
                                                       float* __restrict__ consts) {
    int t = threadIdx.x;   // 0..127
    float s = 0.f;
    for (int i = 0; i < 512; ++i) s += partials[i * 128 + t];
    __shared__ float sh[128];
    sh[t] = s;
    __syncthreads();
    if (t < 64) {
        float sum = sh[t];
        float sumsq = sh[64 + t];
        const float M = (float)((size_t)BB * NN * KK);  // 655360
        float mean = sum / M;
        float var = sumsq / M - mean * mean;
        float inv = 1.0f / sqrtf(var + 1e-5f);
        float A = gamma[t] * inv;
        float Cv = beta[t] - mean * A;
        consts[t] = A;
        consts[64 + t] = Cv;
    }
}

// ---------------- K4: elementwise act over hmax (monotone: max act == act(max h) for A>=0) ----------
__global__ __launch_bounds__(256) void out2_kernel(const float* __restrict__ P1,
                                                   const float* __restrict__ P2,
                                                   const int* __restrict__ edges,
                                                   const float* __restrict__ consts,
                                                   float* __restrict__ out) {
    const int blk = blockIdx.x;        // 512 = b*64 + o
    const int b = blk >> 6;
    const int o = blk & 63;
    const float A = consts[o];
    const float Cv = consts[64 + o];
    float* orow = out + (size_t)blk * NN;   // out[b][o][:]
    if (A >= 0.f) {
#pragma unroll
        for (int it = 0; it < 4; ++it) {
            int idx = (it * 256 + threadIdx.x) * 4;
            float4 v = *(const float4*)(orow + idx);
            float h0 = v.x * A + Cv, h1 = v.y * A + Cv, h2 = v.z * A + Cv, h3 = v.w * A + Cv;
            v.x = h0 >= 0.f ? h0 : 0.2f * h0;
            v.y = h1 >= 0.f ? h1 : 0.2f * h1;
            v.z = h2 >= 0.f ? h2 : 0.2f * h2;
            v.w = h3 >= 0.f ? h3 : 0.2f * h3;
            *(float4*)(orow + idx) = v;
        }
    } else {
        // exact fallback (A<0 flips monotonicity): recompute max over k of act — never
        // taken for this data (gamma ~ N(1,0.01) > 0), wave-uniform branch, deterministic.
        const float* P2b = P2 + (size_t)b * NN * 64;
        for (int n = threadIdx.x; n < NN; n += 256) {
            size_t row = (size_t)b * NN + n;
            float p1 = P1[row * 64 + o];
            const int* e = edges + row * KK;
            float mx = -INFINITY;
            for (int j = 0; j < KK; ++j) {
                float h = p1 + P2b[e[j] * 64 + o];
                float hn = h * A + Cv;
                mx = fmaxf(mx, hn >= 0.f ? hn : 0.2f * hn);
            }
            orow[n] = mx;
        }
    }
}

extern "C" void kernel_launch(void* const* d_in, const int* in_sizes, int n_in,
                              void* d_out, int out_size, void* d_ws, size_t ws_size,
                              hipStream_t stream) {
    const float* x = (const float*)d_in[0];
    const float* W = (const float*)d_in[1];
    const float* gamma = (const float*)d_in[2];
    const float* beta = (const float*)d_in[3];
    float* out = (float*)d_out;

    char* w = (char*)d_ws;
    int* edges = (int*)w;                                        // 2,621,440 B
    float* P1 = (float*)(w + (size_t)BB * NN * KK * 4);          // 8.39 MB
    float* P2 = P1 + (size_t)BB * NN * 64;                       // 8.39 MB
    float* partials = P2 + (size_t)BB * NN * 64;                 // 512*128 floats
    float* consts = partials + 512 * 128;                        // 128 floats
    // pd [NCH][20][32768] + taubuf + budgetbuf alias the P1/P2 region: all dead
    // before proj_kernel writes P1/P2 (stream order). NCH=8 needs 21.25 MB of
    // pd+tau+budget => total ws >= 23.9 MB; fall back to NCH=4 (10.75 MB) if not.
    float* pd = P1;
    const size_t edges_bytes = (size_t)BB * NN * KK * 4;
    const size_t need8 = edges_bytes + ((size_t)8 * KK * NQ + 2 * NQ) * 4;

    if (ws_size >= need8) {
        float* taubuf = pd + (size_t)8 * KK * NQ;
        int* budgetbuf = (int*)(taubuf + NQ);
        knn_part<8><<<128 * 8, 256, 0, stream>>>(x, pd);
        knn_tau<8><<<128, 256, 0, stream>>>(pd, taubuf, budgetbuf);
        knn_collect<<<8192, 256, 0, stream>>>(x, taubuf, budgetbuf, edges);
    } else {
        float* taubuf = pd + (size_t)4 * KK * NQ;
        int* budgetbuf = (int*)(taubuf + NQ);
        knn_part<4><<<128 * 4, 256, 0, stream>>>(x, pd);
        knn_tau<4><<<128, 256, 0, stream>>>(pd, taubuf, budgetbuf);
        knn_collect<<<8192, 256, 0, stream>>>(x, taubuf, budgetbuf, edges);
    }

    proj_kernel<<<2048, 256, 0, stream>>>(x, W, P1, P2);
    stats_kernel<<<512, 256, 0, stream>>>(P1, P2, edges, partials, out);
    finalize_kernel<<<1, 128, 0, stream>>>(partials, gamma, beta, consts);
    out2_kernel<<<512, 256, 0, stream>>>(P1, P2, edges, consts, out);
}

// Round 9
// 241.098 us; speedup vs baseline: 9.4445x; 1.1779x over previous
//
#include <hip/hip_runtime.h>
#include <math.h>

#define BB 8
#define CC 64
#define NN 4096
#define COUT 64
#define KK 20
#define NQ 32768

// NumPy-exact (FMA-free, left-to-right) distance pieces. np.einsum / np.sum
// round every mul and add individually; __f*_rn intrinsics forbid contraction.
__device__ __forceinline__ float np_sq(float ax, float ay, float az) {
    return __fadd_rn(__fadd_rn(__fmul_rn(ax, ax), __fmul_rn(ay, ay)), __fmul_rn(az, az));
}
__device__ __forceinline__ float np_dist(float qx, float qy, float qz, float sqn, float4 p) {
    float dot = __fadd_rn(__fadd_rn(__fmul_rn(qx, p.x), __fmul_rn(qy, p.y)), __fmul_rn(qz, p.z));
    return __fsub_rn(__fadd_rn(sqn, p.w), __fmul_rn(2.0f, dot));
}
__device__ __forceinline__ float min3f(float a, float b, float c) { return fminf(fminf(a, b), c); }
__device__ __forceinline__ float max3f(float a, float b, float c) { return fmaxf(fmaxf(a, b), c); }

// ---------------- K0: pack xyz + |.|^2 once (np-exact) ----------------
__global__ __launch_bounds__(256) void prep_kernel(const float* __restrict__ x,
                                                   float4* __restrict__ pts4) {
    int g = blockIdx.x * 256 + threadIdx.x;   // 128 blocks -> 32768
    int b = g >> 12, n = g & (NN - 1);
    const float* xb = x + (size_t)b * CC * NN;
    float ax = xb[n], ay = xb[NN + n], az = xb[2 * NN + n];
    pts4[g] = make_float4(ax, ay, az, np_sq(ax, ay, az));
}

// ---------------- K1a: per-chunk top-SLOTS distances, carry-4 med3 network ----------------
// No self-mask: d(self) == exactly 0 (fl(sqn+sqn)-fl(2*sqn)) -> strict chunk min ->
// lands in bd[0] of the self-chunk; knn_tau drops that one entry.
template <int NCH, int SLOTS>
__global__ __launch_bounds__(256) void knn_part(const float4* __restrict__ pts4,
                                                float* __restrict__ pd) {
    constexpr int CH = NN / NCH;
    const int grp = blockIdx.x / NCH;
    const int ch = blockIdx.x % NCH;
    const int tid = threadIdx.x;
    const int q = grp * 256 + tid;
    const int b = q >> 12;
    const int n = q & (NN - 1);
    const float4* pb = pts4 + (size_t)b * NN;

    __shared__ float4 pts[CH];
    for (int i = tid; i < CH; i += 256) pts[i] = pb[ch * CH + i];
    __syncthreads();

    float4 me = pb[n];
    const float qx = me.x, qy = me.y, qz = me.z, sqn = me.w;

    float bd[SLOTS];
#pragma unroll
    for (int i = 0; i < SLOTS; ++i) bd[i] = INFINITY;

#pragma unroll 4
    for (int i = 0; i < CH; i += 4) {
        float4 p0 = pts[i + 0], p1 = pts[i + 1], p2 = pts[i + 2], p3 = pts[i + 3];
        float d0 = np_dist(qx, qy, qz, sqn, p0);
        float d1 = np_dist(qx, qy, qz, sqn, p1);
        float d2 = np_dist(qx, qy, qz, sqn, p2);
        float d3 = np_dist(qx, qy, qz, sqn, p3);
        float a0 = fminf(d0, d1), a1 = fmaxf(d0, d1);
        float b0 = fminf(d2, d3), b1 = fmaxf(d2, d3);
        // carry-4: extract min of {a0,b0,bd[s]}, restructure remainder as 2 sorted pairs
#pragma unroll
        for (int s = 0; s < SLOTS; ++s) {
            float mn = min3f(a0, b0, bd[s]);
            float md = __builtin_amdgcn_fmed3f(a0, b0, bd[s]);
            float mx = max3f(a0, b0, bd[s]);
            float t0 = fminf(a1, b1);
            float t1 = fmaxf(a1, b1);
            bd[s] = mn;
            a0 = md; a1 = mx;    // A' = (med3, max3), sorted
            b0 = t0; b1 = t1;    // B' = sort(old a1, old b1)
        }
    }

    // pd layout [chunk][j][q] -> coalesced stores
#pragma unroll
    for (int j = 0; j < SLOTS; ++j) pd[(size_t)(ch * SLOTS + j) * NQ + q] = bd[j];
}

// r-th smallest (r=1..R) of sorted a[LA] u sorted b[LB]; infeasible splits masked by +/-INF
template <int LA, int LB, int R>
__device__ __forceinline__ void mergeR(const float* a, const float* b, float* out) {
#pragma unroll
    for (int r = 1; r <= R; ++r) {
        float best = INFINITY;
#pragma unroll
        for (int j = 0; j <= R; ++j) {
            if (j <= r) {
                float av = (j >= 1) ? ((j <= LA) ? a[j - 1] : INFINITY) : -INFINITY;
                float bv = (r - j >= 1) ? ((r - j <= LB) ? b[r - j - 1] : INFINITY) : -INFINITY;
                best = fminf(best, fmaxf(av, bv));
            }
        }
        out[r - 1] = best;
    }
}

// ---------------- K1b: tau + tie budget from truncated per-chunk lists ----------------
// Safety: tau from truncated lists is exact iff for every chunk the kept-last value
// > tau (then any d <= tau is strictly below the chunk's truncation point -> kept,
// so counts/ties are exact too). Violation (P~4e-9/query) -> budget=-1 -> exact
// fallback in knn_collect.
template <int NCH, int SLOTS>
__global__ __launch_bounds__(256) void knn_tau(const float* __restrict__ pd,
                                               float* __restrict__ taubuf,
                                               int* __restrict__ budgetbuf) {
    const int q = blockIdx.x * 256 + threadIdx.x;   // 128 blocks
    constexpr int CH = NN / NCH;
    constexpr int LEN = SLOTS - 1;                  // effective list length (self dropped)
    const int ch_self = (q & (NN - 1)) / CH;

    float L[NCH][LEN];
#pragma unroll
    for (int c = 0; c < NCH; ++c) {
        float raw[SLOTS];
#pragma unroll
        for (int j = 0; j < SLOTS; ++j) raw[j] = pd[(size_t)(c * SLOTS + j) * NQ + q];
        bool shift = (c == ch_self);   // drop self's exact-0 at slot 0
#pragma unroll
        for (int j = 0; j < LEN; ++j) L[c][j] = shift ? raw[j + 1] : raw[j];
    }

    // sequential merge: T = top-20 of union of the NCH truncated lists
    float T[KK];
    mergeR<LEN, LEN, KK>(L[0], L[1], T);
#pragma unroll
    for (int c = 2; c < NCH; ++c) {
        float M[KK];
        mergeR<KK, LEN, KK>(T, L[c], M);
#pragma unroll
        for (int j = 0; j < KK; ++j) T[j] = M[j];
    }

    float tau = T[KK - 1];
    int cnt_lt = 0;
    bool flag = false;
#pragma unroll
    for (int c = 0; c < NCH; ++c) {
#pragma unroll
        for (int j = 0; j < LEN; ++j) cnt_lt += (L[c][j] < tau) ? 1 : 0;
        flag = flag || (L[c][LEN - 1] <= tau);
    }
    taubuf[q] = tau;
    budgetbuf[q] = flag ? -1 : (KK - cnt_lt);
}

// ---------------- K1c: wave-per-query lane-parallel collect (ballot + prefix) ----------------
__device__ __forceinline__ int prefix_count(unsigned long long mask) {
    int r = __builtin_amdgcn_mbcnt_lo((unsigned)mask, 0);
    return __builtin_amdgcn_mbcnt_hi((unsigned)(mask >> 32), r);
}

__global__ __launch_bounds__(256) void knn_collect(const float4* __restrict__ pts4,
                                                   const float* __restrict__ taubuf,
                                                   const int* __restrict__ budgetbuf,
                                                   int* __restrict__ edges) {
    const int q = blockIdx.x * 4 + (threadIdx.x >> 6);   // 8192 blocks, wave-per-query
    const int lane = threadIdx.x & 63;
    const int b = q >> 12;
    const int n = q & (NN - 1);
    const float4* pb = pts4 + (size_t)b * NN;

    float4 me = pb[n];
    const float qx = me.x, qy = me.y, qz = me.z, sqn = me.w;
    const float tau = taubuf[q];
    const int budget = budgetbuf[q];       // wave-uniform
    int* erow = edges + (size_t)q * KK;

    if (budget >= 0) {
        int cnt = 0, ties = 0;
#pragma unroll 4
        for (int it = 0; it < 64; ++it) {
            int m = it * 64 + lane;
            float4 p = pb[m];                                   // coalesced b128
            float d = np_dist(qx, qy, qz, sqn, p);
            bool valid = (m != n);
            bool is_lt = valid && (d < tau);
            bool is_tie = valid && (d == tau);
            unsigned long long mtie = __ballot(is_tie);
            int tie_rank = ties + prefix_count(mtie);
            bool acc = is_lt || (is_tie && tie_rank < budget);
            unsigned long long macc = __ballot(acc);
            int pos = cnt + prefix_count(macc);
            if (acc && pos < KK) erow[pos] = m;                 // in-order scatter
            cnt += __popcll(macc);
            ties += __popcll(mtie);
        }
        if (lane == 0) {
            for (int j = cnt; j < KK; ++j) erow[j] = (n + 1 + j) & (NN - 1);  // unreachable guard
        }
    } else if (lane == 0) {
        // exact serial fallback: stable top-20 by (d, m) u64 keys — never taken in practice
        unsigned long long bk[KK];
#pragma unroll
        for (int j = 0; j < KK; ++j) bk[j] = ~0ULL;
        for (int m = 0; m < NN; ++m) {
            if (m == n) continue;
            float d = np_dist(qx, qy, qz, sqn, pb[m]);
            unsigned u = __float_as_uint(d);
            u ^= (unsigned)((int)u >> 31) | 0x80000000u;        // order-preserving map
            unsigned long long key = ((unsigned long long)u << 32) | (unsigned)m;
            if (key < bk[KK - 1]) {
#pragma unroll
                for (int s = KK - 1; s >= 1; --s) {
                    bool sh = bk[s - 1] > key;
                    bool here = bk[s] > key;
                    bk[s] = sh ? bk[s - 1] : (here ? key : bk[s]);
                }
                if (bk[0] > key) bk[0] = key;
            }
        }
        for (int j = 0; j < KK; ++j) erow[j] = (int)(bk[j] & 0xFFFFFFFFu);
    }
}

// ---------------- K2: projections P1 = (W1-W2)·x_n, P2 = W2·x_n ----------------
__global__ __launch_bounds__(256) void proj_kernel(const float* __restrict__ x,
                                                   const float* __restrict__ W,
                                                   float* __restrict__ P1,
                                                   float* __restrict__ P2) {
    const int wid = blockIdx.x * 4 + (threadIdx.x >> 6);  // 8192 = 512 row-blocks x 16 o-groups
    const int lane = threadIdx.x & 63;
    const int row_block = wid >> 4;
    const int og = __builtin_amdgcn_readfirstlane(wid & 15);
    const int row = row_block * 64 + lane;
    const int b = row >> 12;
    const int n = row & (NN - 1);
    const float* xb = x + (size_t)b * CC * NN;

    float p1[4] = {0.f, 0.f, 0.f, 0.f};
    float p2[4] = {0.f, 0.f, 0.f, 0.f};
#pragma unroll 8
    for (int c = 0; c < CC; ++c) {
        float xv = xb[(size_t)c * NN + n];                 // coalesced 256B
#pragma unroll
        for (int j = 0; j < 4; ++j) {
            int o = og * 4 + j;
            float w1 = W[o * 2 * CC + c];                  // scalar (s_load) — uniform
            float w2 = W[o * 2 * CC + CC + c];
            p1[j] += (w1 - w2) * xv;
            p2[j] += w2 * xv;
        }
    }
#pragma unroll
    for (int j = 0; j < 4; ++j) {
        int o = og * 4 + j;
        P1[(size_t)row * 64 + o] = p1[j];
        P2[(size_t)row * 64 + o] = p2[j];
    }
}

// ---------------- K3a: BN partial sums + per-row hmax -> transposed store into d_out ----------------
__global__ __launch_bounds__(256) void stats_kernel(const float* __restrict__ P1,
                                                    const float* __restrict__ P2,
                                                    const int* __restrict__ edges,
                                                    float* __restrict__ partials,
                                                    float* __restrict__ out) {
    int blk = blockIdx.x;          // 512 blocks, 64 rows each (all in one batch b)
    int row0 = blk * 64;
    int o = threadIdx.x & 63;
    int rq = threadIdx.x >> 6;
    int b = row0 >> 12;
    int n0 = row0 & (NN - 1);
    const float* P2b = P2 + (size_t)b * NN * 64;
    __shared__ float tile[64][65];
    float s = 0.f, s2 = 0.f;
    for (int rr = rq; rr < 64; rr += 4) {
        int row = row0 + rr;
        float p1 = P1[row * 64 + o];
        const int* e = edges + row * KK;
        float hm = -INFINITY;
#pragma unroll
        for (int j = 0; j < KK; ++j) {
            int ej = e[j];                      // wave-uniform
            float v = p1 + P2b[ej * 64 + o];    // coalesced 256B gather
            s += v;
            s2 += v * v;
            hm = fmaxf(hm, v);
        }
        tile[rr][o] = hm;
    }
    __shared__ float sh1[256], sh2[256];
    sh1[threadIdx.x] = s;
    sh2[threadIdx.x] = s2;
    __syncthreads();
    if (threadIdx.x < 64) {
        float a = sh1[threadIdx.x] + sh1[threadIdx.x + 64] + sh1[threadIdx.x + 128] + sh1[threadIdx.x + 192];
        float a2 = sh2[threadIdx.x] + sh2[threadIdx.x + 64] + sh2[threadIdx.x + 128] + sh2[threadIdx.x + 192];
        partials[blk * 128 + threadIdx.x] = a;
        partials[blk * 128 + 64 + threadIdx.x] = a2;
    }
    int w2 = threadIdx.x >> 6;
    int lane = threadIdx.x & 63;
    for (int o2 = w2 * 16; o2 < w2 * 16 + 16; ++o2) {
        out[((size_t)(b * 64 + o2)) * NN + n0 + lane] = tile[lane][o2];  // coalesced 256B
    }
}

// ---------------- K3b: finalize BN -> A,C consts ----------------
__global__ __launch_bounds__(128) void finalize_kernel(const float* __restrict__ partials,
                                                       const float* __restrict__ gamma,
                                                       const float* __restrict__ beta,
                                                       float* __restrict__ consts) {
    int t = threadIdx.x;   // 0..127
    float s = 0.f;
    for (int i = 0; i < 512; ++i) s += partials[i * 128 + t];
    __shared__ float sh[128];
    sh[t] = s;
    __syncthreads();
    if (t < 64) {
        float sum = sh[t];
        float sumsq = sh[64 + t];
        const float M = (float)((size_t)BB * NN * KK);  // 655360
        float mean = sum / M;
        float var = sumsq / M - mean * mean;
        float inv = 1.0f / sqrtf(var + 1e-5f);
        float A = gamma[t] * inv;
        float Cv = beta[t] - mean * A;
        consts[t] = A;
        consts[64 + t] = Cv;
    }
}

// ---------------- K4: elementwise act over hmax (monotone: max act == act(max h) for A>=0) ----------
__global__ __launch_bounds__(256) void out2_kernel(const float* __restrict__ P1,
                                                   const float* __restrict__ P2,
                                                   const int* __restrict__ edges,
                                                   const float* __restrict__ consts,
                                                   float* __restrict__ out) {
    const int blk = blockIdx.x;        // 512 = b*64 + o
    const int b = blk >> 6;
    const int o = blk & 63;
    const float A = consts[o];
    const float Cv = consts[64 + o];
    float* orow = out + (size_t)blk * NN;   // out[b][o][:]
    if (A >= 0.f) {
#pragma unroll
        for (int it = 0; it < 4; ++it) {
            int idx = (it * 256 + threadIdx.x) * 4;
            float4 v = *(const float4*)(orow + idx);
            float h0 = v.x * A + Cv, h1 = v.y * A + Cv, h2 = v.z * A + Cv, h3 = v.w * A + Cv;
            v.x = h0 >= 0.f ? h0 : 0.2f * h0;
            v.y = h1 >= 0.f ? h1 : 0.2f * h1;
            v.z = h2 >= 0.f ? h2 : 0.2f * h2;
            v.w = h3 >= 0.f ? h3 : 0.2f * h3;
            *(float4*)(orow + idx) = v;
        }
    } else {
        // exact fallback (A<0 flips monotonicity) — never taken for this data
        const float* P2b = P2 + (size_t)b * NN * 64;
        for (int n = threadIdx.x; n < NN; n += 256) {
            size_t row = (size_t)b * NN + n;
            float p1 = P1[row * 64 + o];
            const int* e = edges + row * KK;
            float mx = -INFINITY;
            for (int j = 0; j < KK; ++j) {
                float h = p1 + P2b[e[j] * 64 + o];
                float hn = h * A + Cv;
                mx = fmaxf(mx, hn >= 0.f ? hn : 0.2f * hn);
            }
            orow[n] = mx;
        }
    }
}

extern "C" void kernel_launch(void* const* d_in, const int* in_sizes, int n_in,
                              void* d_out, int out_size, void* d_ws, size_t ws_size,
                              hipStream_t stream) {
    const float* x = (const float*)d_in[0];
    const float* W = (const float*)d_in[1];
    const float* gamma = (const float*)d_in[2];
    const float* beta = (const float*)d_in[3];
    float* out = (float*)d_out;

    char* w = (char*)d_ws;
    int* edges = (int*)w;                                        // 2,621,440 B
    float* P1 = (float*)(w + (size_t)BB * NN * KK * 4);          // 8.39 MB
    float* P2 = P1 + (size_t)BB * NN * 64;                       // 8.39 MB
    float* partials = P2 + (size_t)BB * NN * 64;                 // 256 KB
    float* consts = partials + 512 * 128;                        // 512 B
    float* after = consts + 128;

    // pd [NCH][SLOTS][NQ] aliases P1/P2 head (dead before proj writes them).
    // pts4/taubuf/budgetbuf live past pd; placed beyond pd's extent.
    float* pd = P1;
    const size_t edges_f = (size_t)BB * NN * KK;                 // floats
    const size_t pd8_f = (size_t)8 * 15 * NQ;                    // 15.7 MB
    const size_t fixed_f = edges_f + 2 * (size_t)BB * NN * 64 + 512 * 128 + 128;
    // place pts4 after the fixed P1/P2/partials/consts region (aligned 16B)
    float4* pts4 = (float4*)(after);
    float* taubuf = after + 4 * (size_t)NQ;                      // after pts4 (NQ float4)
    int* budgetbuf = (int*)(taubuf + NQ);
    const size_t need8 = (fixed_f + 4 * (size_t)NQ + 2 * (size_t)NQ) * 4;
    (void)pd8_f;

    prep_kernel<<<128, 256, 0, stream>>>(x, pts4);

    if (ws_size >= need8 && edges_f * 4 + pd8_f * 4 <= (fixed_f - 512 * 128 - 128) * 4) {
        knn_part<8, 15><<<128 * 8, 256, 0, stream>>>(pts4, pd);
        knn_tau<8, 15><<<128, 256, 0, stream>>>(pd, taubuf, budgetbuf);
    } else {
        knn_part<4, 17><<<128 * 4, 256, 0, stream>>>(pts4, pd);
        knn_tau<4, 17><<<128, 256, 0, stream>>>(pd, taubuf, budgetbuf);
    }
    knn_collect<<<8192, 256, 0, stream>>>(pts4, taubuf, budgetbuf, edges);

    proj_kernel<<<2048, 256, 0, stream>>>(x, W, P1, P2);
    stats_kernel<<<512, 256, 0, stream>>>(P1, P2, edges, partials, out);
    finalize_kernel<<<1, 128, 0, stream>>>(partials, gamma, beta, consts);
    out2_kernel<<<512, 256, 0, stream>>>(P1, P2, edges, consts, out);
}

// Round 10
// 218.761 us; speedup vs baseline: 10.4089x; 1.1021x over previous
//
#include <hip/hip_runtime.h>
#include <math.h>

#define BB 8
#define CC 64
#define NN 4096
#define COUT 64
#define KK 20
#define NQ 32768

// NumPy-exact (FMA-free, left-to-right) distance pieces. np.einsum / np.sum
// round every mul and add individually; __f*_rn intrinsics forbid contraction.
__device__ __forceinline__ float np_sq(float ax, float ay, float az) {
    return __fadd_rn(__fadd_rn(__fmul_rn(ax, ax), __fmul_rn(ay, ay)), __fmul_rn(az, az));
}
__device__ __forceinline__ float np_dist(float qx, float qy, float qz, float sqn, float4 p) {
    float dot = __fadd_rn(__fadd_rn(__fmul_rn(qx, p.x), __fmul_rn(qy, p.y)), __fmul_rn(qz, p.z));
    return __fsub_rn(__fadd_rn(sqn, p.w), __fmul_rn(2.0f, dot));
}
__device__ __forceinline__ float min3f(float a, float b, float c) { return fminf(fminf(a, b), c); }
__device__ __forceinline__ float max3f(float a, float b, float c) { return fmaxf(fmaxf(a, b), c); }

// ---------------- K0: pack xyz + |.|^2 once (np-exact) ----------------
__global__ __launch_bounds__(256) void prep_kernel(const float* __restrict__ x,
                                                   float4* __restrict__ pts4) {
    int g = blockIdx.x * 256 + threadIdx.x;   // 128 blocks -> 32768
    int b = g >> 12, n = g & (NN - 1);
    const float* xb = x + (size_t)b * CC * NN;
    float ax = xb[n], ay = xb[NN + n], az = xb[2 * NN + n];
    pts4[g] = make_float4(ax, ay, az, np_sq(ax, ay, az));
}

// ---------------- K1a: per-chunk top-SLOTS distances, carry-4 med3 network ----------------
// No self-mask: d(self) == exactly +0 (fl(sqn+sqn)-fl(2*sqn)) -> strict chunk min ->
// lands in bd[0] of the self-chunk; knn_tau drops that one entry.
template <int NCH, int SLOTS>
__global__ __launch_bounds__(256) void knn_part(const float4* __restrict__ pts4,
                                                float* __restrict__ pd) {
    constexpr int CH = NN / NCH;
    const int grp = blockIdx.x / NCH;
    const int ch = blockIdx.x % NCH;
    const int tid = threadIdx.x;
    const int q = grp * 256 + tid;
    const int b = q >> 12;
    const int n = q & (NN - 1);
    const float4* pb = pts4 + (size_t)b * NN;

    __shared__ float4 pts[CH];
    for (int i = tid; i < CH; i += 256) pts[i] = pb[ch * CH + i];
    __syncthreads();

    float4 me = pb[n];
    const float qx = me.x, qy = me.y, qz = me.z, sqn = me.w;

    float bd[SLOTS];
#pragma unroll
    for (int i = 0; i < SLOTS; ++i) bd[i] = INFINITY;

#pragma unroll 4
    for (int i = 0; i < CH; i += 4) {
        float4 p0 = pts[i + 0], p1 = pts[i + 1], p2 = pts[i + 2], p3 = pts[i + 3];
        float d0 = np_dist(qx, qy, qz, sqn, p0);
        float d1 = np_dist(qx, qy, qz, sqn, p1);
        float d2 = np_dist(qx, qy, qz, sqn, p2);
        float d3 = np_dist(qx, qy, qz, sqn, p3);
        float a0 = fminf(d0, d1), a1 = fmaxf(d0, d1);
        float b0 = fminf(d2, d3), b1 = fmaxf(d2, d3);
        // carry-4: extract min of {a0,b0,bd[s]}, restructure remainder as 2 sorted pairs
#pragma unroll
        for (int s = 0; s < SLOTS; ++s) {
            float mn = min3f(a0, b0, bd[s]);
            float md = __builtin_amdgcn_fmed3f(a0, b0, bd[s]);
            float mx = max3f(a0, b0, bd[s]);
            float t0 = fminf(a1, b1);
            float t1 = fmaxf(a1, b1);
            bd[s] = mn;
            a0 = md; a1 = mx;    // A' = (med3, max3), sorted
            b0 = t0; b1 = t1;    // B' = sort(old a1, old b1)
        }
    }

    // pd layout [chunk][j][q] -> coalesced stores
#pragma unroll
    for (int j = 0; j < SLOTS; ++j) pd[(size_t)(ch * SLOTS + j) * NQ + q] = bd[j];
}

// r-th smallest (r=1..R) of sorted a[LA] u sorted b[LB]; infeasible splits masked by +/-INF
template <int LA, int LB, int R>
__device__ __forceinline__ void mergeR(const float* a, const float* b, float* out) {
#pragma unroll
    for (int r = 1; r <= R; ++r) {
        float best = INFINITY;
#pragma unroll
        for (int j = 0; j <= R; ++j) {
            if (j <= r) {
                float av = (j >= 1) ? ((j <= LA) ? a[j - 1] : INFINITY) : -INFINITY;
                float bv = (r - j >= 1) ? ((r - j <= LB) ? b[r - j - 1] : INFINITY) : -INFINITY;
                best = fminf(best, fmaxf(av, bv));
            }
        }
        out[r - 1] = best;
    }
}

// ---------------- K1b: tau + mode from truncated per-chunk lists ----------------
// Exactness: if every chunk's kept-last > tau, every candidate with d <= tau is in
// the lists -> tau, cnt_lt, cnt_eq all exact. Encoding of budgetbuf:
//   0  -> surplus==0: accepting ALL d<=tau (ascending m) is exactly the stable top-20
//   >0 -> exact tie budget (rank ties, ascending m)            [measure-zero case]
//   -1 -> truncation flag tripped: exact serial fallback       [P ~ 1e-6 * NQ per run]
template <int NCH, int SLOTS>
__global__ __launch_bounds__(256) void knn_tau(const float* __restrict__ pd,
                                               float* __restrict__ taubuf,
                                               int* __restrict__ budgetbuf) {
    const int q = blockIdx.x * 256 + threadIdx.x;   // 128 blocks
    constexpr int CH = NN / NCH;
    constexpr int LEN = SLOTS - 1;                  // effective list length (self dropped)
    const int ch_self = (q & (NN - 1)) / CH;

    float L[NCH][LEN];
#pragma unroll
    for (int c = 0; c < NCH; ++c) {
        float raw[SLOTS];
#pragma unroll
        for (int j = 0; j < SLOTS; ++j) raw[j] = pd[(size_t)(c * SLOTS + j) * NQ + q];
        bool shift = (c == ch_self);   // drop self's exact-0 at slot 0
#pragma unroll
        for (int j = 0; j < LEN; ++j) L[c][j] = shift ? raw[j + 1] : raw[j];
    }

    // sequential merge: T = top-20 of union of the NCH truncated lists
    float T[KK];
    mergeR<LEN, LEN, KK>(L[0], L[1], T);
#pragma unroll
    for (int c = 2; c < NCH; ++c) {
        float M[KK];
        mergeR<KK, LEN, KK>(T, L[c], M);
#pragma unroll
        for (int j = 0; j < KK; ++j) T[j] = M[j];
    }

    float tau = T[KK - 1];
    int cnt_lt = 0, cnt_eq = 0;
    bool flag = false;
#pragma unroll
    for (int c = 0; c < NCH; ++c) {
#pragma unroll
        for (int j = 0; j < LEN; ++j) {
            cnt_lt += (L[c][j] < tau) ? 1 : 0;
            cnt_eq += (L[c][j] == tau) ? 1 : 0;
        }
        flag = flag || (L[c][LEN - 1] <= tau);
    }
    int surplus = cnt_lt + cnt_eq - KK;             // >=0 when flag==0
    taubuf[q] = tau;
    budgetbuf[q] = flag ? -1 : (surplus == 0 ? 0 : (KK - cnt_lt));
}

// ---------------- K1c: wave-per-query lane-parallel collect ----------------
__device__ __forceinline__ int prefix_count(unsigned long long mask) {
    int r = __builtin_amdgcn_mbcnt_lo((unsigned)mask, 0);
    return __builtin_amdgcn_mbcnt_hi((unsigned)(mask >> 32), r);
}

__global__ __launch_bounds__(256) void knn_collect(const float4* __restrict__ pts4,
                                                   const float* __restrict__ taubuf,
                                                   const int* __restrict__ budgetbuf,
                                                   int* __restrict__ edges) {
    const int q = blockIdx.x * 4 + (threadIdx.x >> 6);   // 8192 blocks, wave-per-query
    const int lane = threadIdx.x & 63;
    const int b = q >> 12;
    const int n = q & (NN - 1);
    const float4* pb = pts4 + (size_t)b * NN;

    float4 me = pb[n];
    const float qx = me.x, qy = me.y, qz = me.z, sqn = me.w;
    const float tau = taubuf[q];
    const int budget = budgetbuf[q];       // wave-uniform
    int* erow = edges + (size_t)q * KK;

    if (budget == 0) {
        // FAST PATH: accept all d<=tau (except self), ascending m == stable top-20.
        // Exactly KK accepts guaranteed (surplus==0), so pos < KK always.
        int cnt = 0;
#pragma unroll 4
        for (int it = 0; it < 64; ++it) {
            int m = it * 64 + lane;
            float4 p = pb[m];                                   // coalesced b128 (L2-hot)
            float d = np_dist(qx, qy, qz, sqn, p);
            bool acc = (d <= tau) && (m != n);
            unsigned long long macc = __ballot(acc);
            if (macc) {                                         // skip empty iterations
                int pos = cnt + prefix_count(macc);
                if (acc) erow[pos] = m;
                cnt += __popcll(macc);
            }
        }
    } else if (budget > 0) {
        // tie-rank path (exact; measure-zero): rank d==tau ties by ascending m
        int cnt = 0, ties = 0;
#pragma unroll 4
        for (int it = 0; it < 64; ++it) {
            int m = it * 64 + lane;
            float4 p = pb[m];
            float d = np_dist(qx, qy, qz, sqn, p);
            bool valid = (m != n);
            bool is_lt = valid && (d < tau);
            bool is_tie = valid && (d == tau);
            unsigned long long mtie = __ballot(is_tie);
            int tie_rank = ties + prefix_count(mtie);
            bool acc = is_lt || (is_tie && tie_rank < budget);
            unsigned long long macc = __ballot(acc);
            int pos = cnt + prefix_count(macc);
            if (acc && pos < KK) erow[pos] = m;
            cnt += __popcll(macc);
            ties += __popcll(mtie);
        }
        if (lane == 0) {
            for (int j = cnt; j < KK; ++j) erow[j] = (n + 1 + j) & (NN - 1);  // unreachable guard
        }
    } else if (lane == 0) {
        // exact serial fallback: stable top-20 by (d, m) u64 keys — truncation tripped
        unsigned long long bk[KK];
#pragma unroll
        for (int j = 0; j < KK; ++j) bk[j] = ~0ULL;
        for (int m = 0; m < NN; ++m) {
            if (m == n) continue;
            float d = np_dist(qx, qy, qz, sqn, pb[m]);
            unsigned u = __float_as_uint(d);
            u ^= (unsigned)((int)u >> 31) | 0x80000000u;        // order-preserving map
            unsigned long long key = ((unsigned long long)u << 32) | (unsigned)m;
            if (key < bk[KK - 1]) {
#pragma unroll
                for (int s = KK - 1; s >= 1; --s) {
                    bool sh = bk[s - 1] > key;
                    bool here = bk[s] > key;
                    bk[s] = sh ? bk[s - 1] : (here ? key : bk[s]);
                }
                if (bk[0] > key) bk[0] = key;
            }
        }
        for (int j = 0; j < KK; ++j) erow[j] = (int)(bk[j] & 0xFFFFFFFFu);
    }
}

// ---------------- K2: projections P1 = (W1-W2)·x_n, P2 = W2·x_n ----------------
__global__ __launch_bounds__(256) void proj_kernel(const float* __restrict__ x,
                                                   const float* __restrict__ W,
                                                   float* __restrict__ P1,
                                                   float* __restrict__ P2) {
    const int wid = blockIdx.x * 4 + (threadIdx.x >> 6);  // 8192 = 512 row-blocks x 16 o-groups
    const int lane = threadIdx.x & 63;
    const int row_block = wid >> 4;
    const int og = __builtin_amdgcn_readfirstlane(wid & 15);
    const int row = row_block * 64 + lane;
    const int b = row >> 12;
    const int n = row & (NN - 1);
    const float* xb = x + (size_t)b * CC * NN;

    float p1[4] = {0.f, 0.f, 0.f, 0.f};
    float p2[4] = {0.f, 0.f, 0.f, 0.f};
#pragma unroll 8
    for (int c = 0; c < CC; ++c) {
        float xv = xb[(size_t)c * NN + n];                 // coalesced 256B
#pragma unroll
        for (int j = 0; j < 4; ++j) {
            int o = og * 4 + j;
            float w1 = W[o * 2 * CC + c];                  // scalar (s_load) — uniform
            float w2 = W[o * 2 * CC + CC + c];
            p1[j] += (w1 - w2) * xv;
            p2[j] += w2 * xv;
        }
    }
#pragma unroll
    for (int j = 0; j < 4; ++j) {
        int o = og * 4 + j;
        P1[(size_t)row * 64 + o] = p1[j];
        P2[(size_t)row * 64 + o] = p2[j];
    }
}

// ---------------- K3a: BN partial sums + per-row hmax -> transposed store into d_out ----------------
__global__ __launch_bounds__(256) void stats_kernel(const float* __restrict__ P1,
                                                    const float* __restrict__ P2,
                                                    const int* __restrict__ edges,
                                                    float* __restrict__ partials,
                                                    float* __restrict__ out) {
    int blk = blockIdx.x;          // 512 blocks, 64 rows each (all in one batch b)
    int row0 = blk * 64;
    int o = threadIdx.x & 63;
    int rq = threadIdx.x >> 6;
    int b = row0 >> 12;
    int n0 = row0 & (NN - 1);
    const float* P2b = P2 + (size_t)b * NN * 64;
    __shared__ float tile[64][65];
    float s = 0.f, s2 = 0.f;
    for (int rr = rq; rr < 64; rr += 4) {
        int row = row0 + rr;
        float p1 = P1[row * 64 + o];
        const int* e = edges + row * KK;
        float hm = -INFINITY;
#pragma unroll
        for (int j = 0; j < KK; ++j) {
            int ej = e[j];                      // wave-uniform
            float v = p1 + P2b[ej * 64 + o];    // coalesced 256B gather
            s += v;
            s2 += v * v;
            hm = fmaxf(hm, v);
        }
        tile[rr][o] = hm;
    }
    __shared__ float sh1[256], sh2[256];
    sh1[threadIdx.x] = s;
    sh2[threadIdx.x] = s2;
    __syncthreads();
    if (threadIdx.x < 64) {
        float a = sh1[threadIdx.x] + sh1[threadIdx.x + 64] + sh1[threadIdx.x + 128] + sh1[threadIdx.x + 192];
        float a2 = sh2[threadIdx.x] + sh2[threadIdx.x + 64] + sh2[threadIdx.x + 128] + sh2[threadIdx.x + 192];
        partials[blk * 128 + threadIdx.x] = a;
        partials[blk * 128 + 64 + threadIdx.x] = a2;
    }
    int w2 = threadIdx.x >> 6;
    int lane = threadIdx.x & 63;
    for (int o2 = w2 * 16; o2 < w2 * 16 + 16; ++o2) {
        out[((size_t)(b * 64 + o2)) * NN + n0 + lane] = tile[lane][o2];  // coalesced 256B
    }
}

// ---------------- K3b: finalize BN -> A,C consts ----------------
__global__ __launch_bounds__(128) void finalize_kernel(const float* __restrict__ partials,
                                                       const float* __restrict__ gamma,
                                                       const float* __restrict__ beta,
                                                       float* __restrict__ consts) {
    int t = threadIdx.x;   // 0..127
    float s = 0.f;
    for (int i = 0; i < 512; ++i) s += partials[i * 128 + t];
    __shared__ float sh[128];
    sh[t] = s;
    __syncthreads();
    if (t < 64) {
        float sum = sh[t];
        float sumsq = sh[64 + t];
        const float M = (float)((size_t)BB * NN * KK);  // 655360
        float mean = sum / M;
        float var = sumsq / M - mean * mean;
        float inv = 1.0f / sqrtf(var + 1e-5f);
        float A = gamma[t] * inv;
        float Cv = beta[t] - mean * A;
        consts[t] = A;
        consts[64 + t] = Cv;
    }
}

// ---------------- K4: elementwise act over hmax (monotone: max act == act(max h) for A>=0) ----------
__global__ __launch_bounds__(256) void out2_kernel(const float* __restrict__ P1,
                                                   const float* __restrict__ P2,
                                                   const int* __restrict__ edges,
                                                   const float* __restrict__ consts,
                                                   float* __restrict__ out) {
    const int blk = blockIdx.x;        // 512 = b*64 + o
    const int b = blk >> 6;
    const int o = blk & 63;
    const float A = consts[o];
    const float Cv = consts[64 + o];
    float* orow = out + (size_t)blk * NN;   // out[b][o][:]
    if (A >= 0.f) {
#pragma unroll
        for (int it = 0; it < 4; ++it) {
            int idx = (it * 256 + threadIdx.x) * 4;
            float4 v = *(const float4*)(orow + idx);
            float h0 = v.x * A + Cv, h1 = v.y * A + Cv, h2 = v.z * A + Cv, h3 = v.w * A + Cv;
            v.x = h0 >= 0.f ? h0 : 0.2f * h0;
            v.y = h1 >= 0.f ? h1 : 0.2f * h1;
            v.z = h2 >= 0.f ? h2 : 0.2f * h2;
            v.w = h3 >= 0.f ? h3 : 0.2f * h3;
            *(float4*)(orow + idx) = v;
        }
    } else {
        // exact fallback (A<0 flips monotonicity) — never taken for this data
        const float* P2b = P2 + (size_t)b * NN * 64;
        for (int n = threadIdx.x; n < NN; n += 256) {
            size_t row = (size_t)b * NN + n;
            float p1 = P1[row * 64 + o];
            const int* e = edges + row * KK;
            float mx = -INFINITY;
            for (int j = 0; j < KK; ++j) {
                float h = p1 + P2b[e[j] * 64 + o];
                float hn = h * A + Cv;
                mx = fmaxf(mx, hn >= 0.f ? hn : 0.2f * hn);
            }
            orow[n] = mx;
        }
    }
}

extern "C" void kernel_launch(void* const* d_in, const int* in_sizes, int n_in,
                              void* d_out, int out_size, void* d_ws, size_t ws_size,
                              hipStream_t stream) {
    const float* x = (const float*)d_in[0];
    const float* W = (const float*)d_in[1];
    const float* gamma = (const float*)d_in[2];
    const float* beta = (const float*)d_in[3];
    float* out = (float*)d_out;

    // De-aliased layout: only pd shares memory (with P1/P2, dead before proj writes).
    char* w = (char*)d_ws;
    float4* pts4      = (float4*)(w + 0);                 //   524288 B
    float*  taubuf    = (float*)(w + 524288);             //   131072 B
    int*    budgetbuf = (int*)(w + 655360);               //   131072 B
    float*  partials  = (float*)(w + 786432);             //   262144 B
    float*  consts    = (float*)(w + 1048576);            //      512 B (pad to 1024)
    int*    edges     = (int*)(w + 1049600);              //  2621440 B
    char*   region    = w + 3671040;
    float*  P1 = (float*)region;                          //  8388608 B
    float*  P2 = P1 + (size_t)NQ * 64;                    //  8388608 B
    float*  pd = (float*)region;                          // aliases P1/P2 head

    const size_t need16 = 3671040 + (size_t)16 * 11 * NQ * 4;   // 26,739,712 B
    // tier B footprint: 3671040 + 16777216 = 20,448,256 B (proven to fit in R9)

    prep_kernel<<<128, 256, 0, stream>>>(x, pts4);
    if (ws_size >= need16) {
        knn_part<16, 11><<<128 * 16, 256, 0, stream>>>(pts4, pd);
        knn_tau<16, 11><<<128, 256, 0, stream>>>(pd, taubuf, budgetbuf);
    } else {
        knn_part<8, 13><<<128 * 8, 256, 0, stream>>>(pts4, pd);
        knn_tau<8, 13><<<128, 256, 0, stream>>>(pd, taubuf, budgetbuf);
    }
    knn_collect<<<8192, 256, 0, stream>>>(pts4, taubuf, budgetbuf, edges);

    proj_kernel<<<2048, 256, 0, stream>>>(x, W, P1, P2);
    stats_kernel<<<512, 256, 0, stream>>>(P1, P2, edges, partials, out);
    finalize_kernel<<<1, 128, 0, stream>>>(partials, gamma, beta, consts);
    out2_kernel<<<512, 256, 0, stream>>>(P1, P2, edges, consts, out);
}

// Round 11
// 199.506 us; speedup vs baseline: 11.4135x; 1.0965x over previous
//
#include <hip/hip_runtime.h>
#include <math.h>

#define BB 8
#define CC 64
#define NN 4096
#define COUT 64
#define KK 20
#define NQ 32768

// NumPy-exact (FMA-free, left-to-right) distance pieces. np.einsum / np.sum
// round every mul and add individually; __f*_rn intrinsics forbid contraction.
__device__ __forceinline__ float np_sq(float ax, float ay, float az) {
    return __fadd_rn(__fadd_rn(__fmul_rn(ax, ax), __fmul_rn(ay, ay)), __fmul_rn(az, az));
}
__device__ __forceinline__ float np_dist(float qx, float qy, float qz, float sqn, float4 p) {
    float dot = __fadd_rn(__fadd_rn(__fmul_rn(qx, p.x), __fmul_rn(qy, p.y)), __fmul_rn(qz, p.z));
    return __fsub_rn(__fadd_rn(sqn, p.w), __fmul_rn(2.0f, dot));
}
__device__ __forceinline__ float min3f(float a, float b, float c) { return fminf(fminf(a, b), c); }
__device__ __forceinline__ float max3f(float a, float b, float c) { return fmaxf(fmaxf(a, b), c); }

// ---------------- K0: pack xyz + |.|^2 once (np-exact) ----------------
__global__ __launch_bounds__(256) void prep_kernel(const float* __restrict__ x,
                                                   float4* __restrict__ pts4) {
    int g = blockIdx.x * 256 + threadIdx.x;   // 128 blocks -> 32768
    int b = g >> 12, n = g & (NN - 1);
    const float* xb = x + (size_t)b * CC * NN;
    float ax = xb[n], ay = xb[NN + n], az = xb[2 * NN + n];
    pts4[g] = make_float4(ax, ay, az, np_sq(ax, ay, az));
}

// ---------------- K1a: per-chunk top-SLOTS distances, carry-4 med3 network ----------------
// No self-mask: d(self) == exactly +0 (fl(sqn+sqn)-fl(2*sqn)) -> strict chunk min ->
// lands in bd[0] of the self-chunk; knn_tau drops that one entry.
template <int NCH, int SLOTS>
__global__ __launch_bounds__(256) void knn_part(const float4* __restrict__ pts4,
                                                float* __restrict__ pd) {
    constexpr int CH = NN / NCH;
    const int grp = blockIdx.x / NCH;
    const int ch = blockIdx.x % NCH;
    const int tid = threadIdx.x;
    const int q = grp * 256 + tid;
    const int b = q >> 12;
    const int n = q & (NN - 1);
    const float4* pb = pts4 + (size_t)b * NN;

    __shared__ float4 pts[CH];
    for (int i = tid; i < CH; i += 256) pts[i] = pb[ch * CH + i];
    __syncthreads();

    float4 me = pb[n];
    const float qx = me.x, qy = me.y, qz = me.z, sqn = me.w;

    float bd[SLOTS];
#pragma unroll
    for (int i = 0; i < SLOTS; ++i) bd[i] = INFINITY;

#pragma unroll 4
    for (int i = 0; i < CH; i += 4) {
        float4 p0 = pts[i + 0], p1 = pts[i + 1], p2 = pts[i + 2], p3 = pts[i + 3];
        float d0 = np_dist(qx, qy, qz, sqn, p0);
        float d1 = np_dist(qx, qy, qz, sqn, p1);
        float d2 = np_dist(qx, qy, qz, sqn, p2);
        float d3 = np_dist(qx, qy, qz, sqn, p3);
        float a0 = fminf(d0, d1), a1 = fmaxf(d0, d1);
        float b0 = fminf(d2, d3), b1 = fmaxf(d2, d3);
        // carry-4: extract min of {a0,b0,bd[s]}, restructure remainder as 2 sorted pairs
#pragma unroll
        for (int s = 0; s < SLOTS; ++s) {
            float mn = min3f(a0, b0, bd[s]);
            float md = __builtin_amdgcn_fmed3f(a0, b0, bd[s]);
            float mx = max3f(a0, b0, bd[s]);
            float t0 = fminf(a1, b1);
            float t1 = fmaxf(a1, b1);
            bd[s] = mn;
            a0 = md; a1 = mx;    // A' = (med3, max3), sorted
            b0 = t0; b1 = t1;    // B' = sort(old a1, old b1)
        }
    }

    // pd layout [chunk][j][q] -> coalesced stores
#pragma unroll
    for (int j = 0; j < SLOTS; ++j) pd[(size_t)(ch * SLOTS + j) * NQ + q] = bd[j];
}

// r-th smallest (r=1..R) of sorted a[LA] u sorted b[LB]; infeasible splits masked by +/-INF
template <int LA, int LB, int R>
__device__ __forceinline__ void mergeR(const float* a, const float* b, float* out) {
#pragma unroll
    for (int r = 1; r <= R; ++r) {
        float best = INFINITY;
#pragma unroll
        for (int j = 0; j <= R; ++j) {
            if (j <= r) {
                float av = (j >= 1) ? ((j <= LA) ? a[j - 1] : INFINITY) : -INFINITY;
                float bv = (r - j >= 1) ? ((r - j <= LB) ? b[r - j - 1] : INFINITY) : -INFINITY;
                best = fminf(best, fmaxf(av, bv));
            }
        }
        out[r - 1] = best;
    }
}

// ---------------- K1b: tau + mode from truncated per-chunk lists ----------------
// Exactness: if every chunk's kept-last > tau, every candidate with d <= tau is in
// the lists -> tau, cnt_lt, cnt_eq all exact. Encoding of budgetbuf:
//   0  -> surplus==0: accepting ALL d<=tau (ascending m) is exactly the stable top-20
//   >0 -> exact tie budget (rank ties, ascending m)            [measure-zero case]
//   -1 -> truncation flag tripped: exact serial fallback       [P ~ 1e-6 * NQ per run]
template <int NCH, int SLOTS>
__global__ __launch_bounds__(256) void knn_tau(const float* __restrict__ pd,
                                               float* __restrict__ taubuf,
                                               int* __restrict__ budgetbuf) {
    const int q = blockIdx.x * 256 + threadIdx.x;   // 128 blocks
    constexpr int CH = NN / NCH;
    constexpr int LEN = SLOTS - 1;                  // effective list length (self dropped)
    const int ch_self = (q & (NN - 1)) / CH;

    float L[NCH][LEN];
#pragma unroll
    for (int c = 0; c < NCH; ++c) {
        float raw[SLOTS];
#pragma unroll
        for (int j = 0; j < SLOTS; ++j) raw[j] = pd[(size_t)(c * SLOTS + j) * NQ + q];
        bool shift = (c == ch_self);   // drop self's exact-0 at slot 0
#pragma unroll
        for (int j = 0; j < LEN; ++j) L[c][j] = shift ? raw[j + 1] : raw[j];
    }

    // sequential merge: T = top-20 of union of the NCH truncated lists
    float T[KK];
    mergeR<LEN, LEN, KK>(L[0], L[1], T);
#pragma unroll
    for (int c = 2; c < NCH; ++c) {
        float M[KK];
        mergeR<KK, LEN, KK>(T, L[c], M);
#pragma unroll
        for (int j = 0; j < KK; ++j) T[j] = M[j];
    }

    float tau = T[KK - 1];
    int cnt_lt = 0, cnt_eq = 0;
    bool flag = false;
#pragma unroll
    for (int c = 0; c < NCH; ++c) {
#pragma unroll
        for (int j = 0; j < LEN; ++j) {
            cnt_lt += (L[c][j] < tau) ? 1 : 0;
            cnt_eq += (L[c][j] == tau) ? 1 : 0;
        }
        flag = flag || (L[c][LEN - 1] <= tau);
    }
    int surplus = cnt_lt + cnt_eq - KK;             // >=0 when flag==0
    taubuf[q] = tau;
    budgetbuf[q] = flag ? -1 : (surplus == 0 ? 0 : (KK - cnt_lt));
}

// ---------------- K1c: collect ----------------
__device__ __forceinline__ int prefix_count(unsigned long long mask) {
    int r = __builtin_amdgcn_mbcnt_lo((unsigned)mask, 0);
    return __builtin_amdgcn_mbcnt_hi((unsigned)(mask >> 32), r);
}

// single-query exact collect (R10 logic): handles budget==0 / >0 / -1
__device__ void collect_one(const float4* __restrict__ pb, int n, float qx, float qy,
                            float qz, float sqn, float tau, int budget, int lane,
                            int* __restrict__ erow) {
    if (budget == 0) {
        int cnt = 0;
        for (int it = 0; it < 64; ++it) {
            int m = it * 64 + lane;
            float4 p = pb[m];
            float d = np_dist(qx, qy, qz, sqn, p);
            bool acc = (d <= tau) && (m != n);
            unsigned long long macc = __ballot(acc);
            if (macc) {
                int pos = cnt + prefix_count(macc);
                if (acc) erow[pos] = m;
                cnt += __popcll(macc);
            }
        }
    } else if (budget > 0) {
        int cnt = 0, ties = 0;
        for (int it = 0; it < 64; ++it) {
            int m = it * 64 + lane;
            float4 p = pb[m];
            float d = np_dist(qx, qy, qz, sqn, p);
            bool valid = (m != n);
            bool is_lt = valid && (d < tau);
            bool is_tie = valid && (d == tau);
            unsigned long long mtie = __ballot(is_tie);
            int tie_rank = ties + prefix_count(mtie);
            bool acc = is_lt || (is_tie && tie_rank < budget);
            unsigned long long macc = __ballot(acc);
            int pos = cnt + prefix_count(macc);
            if (acc && pos < KK) erow[pos] = m;
            cnt += __popcll(macc);
            ties += __popcll(mtie);
        }
        if (lane == 0) {
            for (int j = cnt; j < KK; ++j) erow[j] = (n + 1 + j) & (NN - 1);  // unreachable guard
        }
    } else if (lane == 0) {
        // exact serial fallback: stable top-20 by (d, m) u64 keys — truncation tripped
        unsigned long long bk[KK];
#pragma unroll
        for (int j = 0; j < KK; ++j) bk[j] = ~0ULL;
        for (int m = 0; m < NN; ++m) {
            if (m == n) continue;
            float d = np_dist(qx, qy, qz, sqn, pb[m]);
            unsigned u = __float_as_uint(d);
            u ^= (unsigned)((int)u >> 31) | 0x80000000u;        // order-preserving map
            unsigned long long key = ((unsigned long long)u << 32) | (unsigned)m;
            if (key < bk[KK - 1]) {
#pragma unroll
                for (int s = KK - 1; s >= 1; --s) {
                    bool sh = bk[s - 1] > key;
                    bool here = bk[s] > key;
                    bk[s] = sh ? bk[s - 1] : (here ? key : bk[s]);
                }
                if (bk[0] > key) bk[0] = key;
            }
        }
        for (int j = 0; j < KK; ++j) erow[j] = (int)(bk[j] & 0xFFFFFFFFu);
    }
}

// 4 queries per wave: one candidate load feeds 4 distance tests (L2 traffic /4).
// 2048 blocks x 256 threads; wave w handles queries (blockIdx*4+w)*4 .. +3 (same batch).
__global__ __launch_bounds__(256) void knn_collect(const float4* __restrict__ pts4,
                                                   const float* __restrict__ taubuf,
                                                   const int* __restrict__ budgetbuf,
                                                   int* __restrict__ edges) {
    const int wave = threadIdx.x >> 6;
    const int lane = threadIdx.x & 63;
    const int q0 = (blockIdx.x * 4 + wave) * 4;
    const int b = q0 >> 12;                          // 4 | 4096 -> same batch for all 4
    const float4* pb = pts4 + (size_t)b * NN;

    int nj[4], bj[4];
    float qxj[4], qyj[4], qzj[4], sqj[4], tj[4];
#pragma unroll
    for (int j = 0; j < 4; ++j) {
        int q = q0 + j;
        nj[j] = q & (NN - 1);
        float4 me = pb[nj[j]];                       // uniform -> broadcast
        qxj[j] = me.x; qyj[j] = me.y; qzj[j] = me.z; sqj[j] = me.w;
        tj[j] = taubuf[q];
        bj[j] = budgetbuf[q];
    }

    if ((bj[0] | bj[1] | bj[2] | bj[3]) == 0) {      // wave-uniform fast gate
        int cnt[4] = {0, 0, 0, 0};
        for (int it = 0; it < 64; ++it) {
            int m = it * 64 + lane;
            float4 p = pb[m];                        // one coalesced b128 for 4 queries
#pragma unroll
            for (int j = 0; j < 4; ++j) {
                float d = np_dist(qxj[j], qyj[j], qzj[j], sqj[j], p);
                bool acc = (d <= tj[j]) && (m != nj[j]);
                unsigned long long mk = __ballot(acc);
                if (mk) {
                    int pos = cnt[j] + prefix_count(mk);
                    if (acc) edges[(size_t)(q0 + j) * KK + pos] = m;
                    cnt[j] += __popcll(mk);
                }
            }
        }
    } else {
        // rare: at least one query needs tie/fallback handling — do all 4 exactly
#pragma unroll
        for (int j = 0; j < 4; ++j) {
            collect_one(pb, nj[j], qxj[j], qyj[j], qzj[j], sqj[j], tj[j], bj[j], lane,
                        edges + (size_t)(q0 + j) * KK);
        }
    }
}

// ---------------- K2: projections P1 = (W1-W2)·x_n, P2 = W2·x_n ----------------
__global__ __launch_bounds__(256) void proj_kernel(const float* __restrict__ x,
                                                   const float* __restrict__ W,
                                                   float* __restrict__ P1,
                                                   float* __restrict__ P2) {
    const int wid = blockIdx.x * 4 + (threadIdx.x >> 6);  // 8192 = 512 row-blocks x 16 o-groups
    const int lane = threadIdx.x & 63;
    const int row_block = wid >> 4;
    const int og = __builtin_amdgcn_readfirstlane(wid & 15);
    const int row = row_block * 64 + lane;
    const int b = row >> 12;
    const int n = row & (NN - 1);
    const float* xb = x + (size_t)b * CC * NN;

    float p1[4] = {0.f, 0.f, 0.f, 0.f};
    float p2[4] = {0.f, 0.f, 0.f, 0.f};
#pragma unroll 8
    for (int c = 0; c < CC; ++c) {
        float xv = xb[(size_t)c * NN + n];                 // coalesced 256B
#pragma unroll
        for (int j = 0; j < 4; ++j) {
            int o = og * 4 + j;
            float w1 = W[o * 2 * CC + c];                  // scalar (s_load) — uniform
            float w2 = W[o * 2 * CC + CC + c];
            p1[j] += (w1 - w2) * xv;
            p2[j] += w2 * xv;
        }
    }
#pragma unroll
    for (int j = 0; j < 4; ++j) {
        int o = og * 4 + j;
        P1[(size_t)row * 64 + o] = p1[j];
        P2[(size_t)row * 64 + o] = p2[j];
    }
}

// ---------------- K3a: BN partial sums + per-row hmax -> transposed store into d_out ----------------
__global__ __launch_bounds__(256) void stats_kernel(const float* __restrict__ P1,
                                                    const float* __restrict__ P2,
                                                    const int* __restrict__ edges,
                                                    float* __restrict__ partials,
                                                    float* __restrict__ out) {
    int blk = blockIdx.x;          // 512 blocks, 64 rows each (all in one batch b)
    int row0 = blk * 64;
    int o = threadIdx.x & 63;
    int rq = threadIdx.x >> 6;
    int b = row0 >> 12;
    int n0 = row0 & (NN - 1);
    const float* P2b = P2 + (size_t)b * NN * 64;
    __shared__ float tile[64][65];
    float s = 0.f, s2 = 0.f;
    for (int rr = rq; rr < 64; rr += 4) {
        int row = row0 + rr;
        float p1 = P1[row * 64 + o];
        const int* e = edges + row * KK;
        float hm = -INFINITY;
#pragma unroll
        for (int j = 0; j < KK; ++j) {
            int ej = e[j];                      // wave-uniform
            float v = p1 + P2b[ej * 64 + o];    // coalesced 256B gather
            s += v;
            s2 += v * v;
            hm = fmaxf(hm, v);
        }
        tile[rr][o] = hm;
    }
    __shared__ float sh1[256], sh2[256];
    sh1[threadIdx.x] = s;
    sh2[threadIdx.x] = s2;
    __syncthreads();
    if (threadIdx.x < 64) {
        float a = sh1[threadIdx.x] + sh1[threadIdx.x + 64] + sh1[threadIdx.x + 128] + sh1[threadIdx.x + 192];
        float a2 = sh2[threadIdx.x] + sh2[threadIdx.x + 64] + sh2[threadIdx.x + 128] + sh2[threadIdx.x + 192];
        partials[blk * 128 + threadIdx.x] = a;
        partials[blk * 128 + 64 + threadIdx.x] = a2;
    }
    int w2 = threadIdx.x >> 6;
    int lane = threadIdx.x & 63;
    for (int o2 = w2 * 16; o2 < w2 * 16 + 16; ++o2) {
        out[((size_t)(b * 64 + o2)) * NN + n0 + lane] = tile[lane][o2];  // coalesced 256B
    }
}

// ---------------- K3b: finalize BN -> A,C consts ----------------
__global__ __launch_bounds__(128) void finalize_kernel(const float* __restrict__ partials,
                                                       const float* __restrict__ gamma,
                                                       const float* __restrict__ beta,
                                                       float* __restrict__ consts) {
    int t = threadIdx.x;   // 0..127
    float s = 0.f;
    for (int i = 0; i < 512; ++i) s += partials[i * 128 + t];
    __shared__ float sh[128];
    sh[t] = s;
    __syncthreads();
    if (t < 64) {
        float sum = sh[t];
        float sumsq = sh[64 + t];
        const float M = (float)((size_t)BB * NN * KK);  // 655360
        float mean = sum / M;
        float var = sumsq / M - mean * mean;
        float inv = 1.0f / sqrtf(var + 1e-5f);
        float A = gamma[t] * inv;
        float Cv = beta[t] - mean * A;
        consts[t] = A;
        consts[64 + t] = Cv;
    }
}

// ---------------- K4: elementwise act over hmax (monotone: max act == act(max h) for A>=0) ----------
__global__ __launch_bounds__(256) void out2_kernel(const float* __restrict__ P1,
                                                   const float* __restrict__ P2,
                                                   const int* __restrict__ edges,
                                                   const float* __restrict__ consts,
                                                   float* __restrict__ out) {
    const int blk = blockIdx.x;        // 512 = b*64 + o
    const int b = blk >> 6;
    const int o = blk & 63;
    const float A = consts[o];
    const float Cv = consts[64 + o];
    float* orow = out + (size_t)blk * NN;   // out[b][o][:]
    if (A >= 0.f) {
#pragma unroll
        for (int it = 0; it < 4; ++it) {
            int idx = (it * 256 + threadIdx.x) * 4;
            float4 v = *(const float4*)(orow + idx);
            float h0 = v.x * A + Cv, h1 = v.y * A + Cv, h2 = v.z * A + Cv, h3 = v.w * A + Cv;
            v.x = h0 >= 0.f ? h0 : 0.2f * h0;
            v.y = h1 >= 0.f ? h1 : 0.2f * h1;
            v.z = h2 >= 0.f ? h2 : 0.2f * h2;
            v.w = h3 >= 0.f ? h3 : 0.2f * h3;
            *(float4*)(orow + idx) = v;
        }
    } else {
        // exact fallback (A<0 flips monotonicity) — never taken for this data
        const float* P2b = P2 + (size_t)b * NN * 64;
        for (int n = threadIdx.x; n < NN; n += 256) {
            size_t row = (size_t)b * NN + n;
            float p1 = P1[row * 64 + o];
            const int* e = edges + row * KK;
            float mx = -INFINITY;
            for (int j = 0; j < KK; ++j) {
                float h = p1 + P2b[e[j] * 64 + o];
                float hn = h * A + Cv;
                mx = fmaxf(mx, hn >= 0.f ? hn : 0.2f * hn);
            }
            orow[n] = mx;
        }
    }
}

extern "C" void kernel_launch(void* const* d_in, const int* in_sizes, int n_in,
                              void* d_out, int out_size, void* d_ws, size_t ws_size,
                              hipStream_t stream) {
    const float* x = (const float*)d_in[0];
    const float* W = (const float*)d_in[1];
    const float* gamma = (const float*)d_in[2];
    const float* beta = (const float*)d_in[3];
    float* out = (float*)d_out;

    // De-aliased layout: only pd shares memory (with P1/P2, dead before proj writes).
    char* w = (char*)d_ws;
    float4* pts4      = (float4*)(w + 0);                 //   524288 B
    float*  taubuf    = (float*)(w + 524288);             //   131072 B
    int*    budgetbuf = (int*)(w + 655360);               //   131072 B
    float*  partials  = (float*)(w + 786432);             //   262144 B
    float*  consts    = (float*)(w + 1048576);            //      512 B (pad to 1024)
    int*    edges     = (int*)(w + 1049600);              //  2621440 B
    char*   region    = w + 3671040;
    float*  P1 = (float*)region;                          //  8388608 B
    float*  P2 = P1 + (size_t)NQ * 64;                    //  8388608 B
    float*  pd = (float*)region;                          // aliases P1/P2 head

    const size_t need16 = 3671040 + (size_t)16 * 11 * NQ * 4;   // 26,739,712 B

    prep_kernel<<<128, 256, 0, stream>>>(x, pts4);
    if (ws_size >= need16) {
        knn_part<16, 11><<<128 * 16, 256, 0, stream>>>(pts4, pd);
        knn_tau<16, 11><<<128, 256, 0, stream>>>(pd, taubuf, budgetbuf);
    } else {
        knn_part<8, 13><<<128 * 8, 256, 0, stream>>>(pts4, pd);
        knn_tau<8, 13><<<128, 256, 0, stream>>>(pd, taubuf, budgetbuf);
    }
    knn_collect<<<2048, 256, 0, stream>>>(pts4, taubuf, budgetbuf, edges);

    proj_kernel<<<2048, 256, 0, stream>>>(x, W, P1, P2);
    stats_kernel<<<512, 256, 0, stream>>>(P1, P2, edges, partials, out);
    finalize_kernel<<<1, 128, 0, stream>>>(partials, gamma, beta, consts);
    out2_kernel<<<512, 256, 0, stream>>>(P1, P2, edges, consts, out);
}

// Round 12
// 193.062 us; speedup vs baseline: 11.7944x; 1.0334x over previous
//
#include <hip/hip_runtime.h>
#include <math.h>

#define BB 8
#define CC 64
#define NN 4096
#define COUT 64
#define KK 20
#define NQ 32768

// NumPy-exact (FMA-free, left-to-right) distance pieces. np.einsum / np.sum
// round every mul and add individually; __f*_rn intrinsics forbid contraction.
__device__ __forceinline__ float np_sq(float ax, float ay, float az) {
    return __fadd_rn(__fadd_rn(__fmul_rn(ax, ax), __fmul_rn(ay, ay)), __fmul_rn(az, az));
}
__device__ __forceinline__ float np_dist(float qx, float qy, float qz, float sqn, float4 p) {
    float dot = __fadd_rn(__fadd_rn(__fmul_rn(qx, p.x), __fmul_rn(qy, p.y)), __fmul_rn(qz, p.z));
    return __fsub_rn(__fadd_rn(sqn, p.w), __fmul_rn(2.0f, dot));
}
__device__ __forceinline__ float min3f(float a, float b, float c) { return fminf(fminf(a, b), c); }
__device__ __forceinline__ float max3f(float a, float b, float c) { return fmaxf(fmaxf(a, b), c); }

// ---------------- K0: pack xyz + |.|^2 once (np-exact) ----------------
__global__ __launch_bounds__(256) void prep_kernel(const float* __restrict__ x,
                                                   float4* __restrict__ pts4) {
    int g = blockIdx.x * 256 + threadIdx.x;   // 128 blocks -> 32768
    int b = g >> 12, n = g & (NN - 1);
    const float* xb = x + (size_t)b * CC * NN;
    float ax = xb[n], ay = xb[NN + n], az = xb[2 * NN + n];
    pts4[g] = make_float4(ax, ay, az, np_sq(ax, ay, az));
}

// ---------------- K1a: per-chunk top-SLOTS distances, carry-4 med3 network ----------------
// No self-mask: d(self) == exactly +0 (fl(sqn+sqn)-fl(2*sqn)) -> strict chunk min ->
// lands in bd[0] of the self-chunk; knn_tau drops that one entry.
template <int NCH, int SLOTS>
__global__ __launch_bounds__(256) void knn_part(const float4* __restrict__ pts4,
                                                float* __restrict__ pd) {
    constexpr int CH = NN / NCH;
    const int grp = blockIdx.x / NCH;
    const int ch = blockIdx.x % NCH;
    const int tid = threadIdx.x;
    const int q = grp * 256 + tid;
    const int b = q >> 12;
    const int n = q & (NN - 1);
    const float4* pb = pts4 + (size_t)b * NN;

    __shared__ float4 pts[CH];
    for (int i = tid; i < CH; i += 256) pts[i] = pb[ch * CH + i];
    __syncthreads();

    float4 me = pb[n];
    const float qx = me.x, qy = me.y, qz = me.z, sqn = me.w;

    float bd[SLOTS];
#pragma unroll
    for (int i = 0; i < SLOTS; ++i) bd[i] = INFINITY;

#pragma unroll 4
    for (int i = 0; i < CH; i += 4) {
        float4 p0 = pts[i + 0], p1 = pts[i + 1], p2 = pts[i + 2], p3 = pts[i + 3];
        float d0 = np_dist(qx, qy, qz, sqn, p0);
        float d1 = np_dist(qx, qy, qz, sqn, p1);
        float d2 = np_dist(qx, qy, qz, sqn, p2);
        float d3 = np_dist(qx, qy, qz, sqn, p3);
        float a0 = fminf(d0, d1), a1 = fmaxf(d0, d1);
        float b0 = fminf(d2, d3), b1 = fmaxf(d2, d3);
        // carry-4: extract min of {a0,b0,bd[s]}, restructure remainder as 2 sorted pairs
#pragma unroll
        for (int s = 0; s < SLOTS; ++s) {
            float mn = min3f(a0, b0, bd[s]);
            float md = __builtin_amdgcn_fmed3f(a0, b0, bd[s]);
            float mx = max3f(a0, b0, bd[s]);
            float t0 = fminf(a1, b1);
            float t1 = fmaxf(a1, b1);
            bd[s] = mn;
            a0 = md; a1 = mx;    // A' = (med3, max3), sorted
            b0 = t0; b1 = t1;    // B' = sort(old a1, old b1)
        }
    }

    // pd layout [chunk][j][q] -> coalesced stores
#pragma unroll
    for (int j = 0; j < SLOTS; ++j) pd[(size_t)(ch * SLOTS + j) * NQ + q] = bd[j];
}

// r-th smallest (r=1..R) of sorted a[LA] u sorted b[LB]; infeasible splits masked by +/-INF
template <int LA, int LB, int R>
__device__ __forceinline__ void mergeR(const float* a, const float* b, float* out) {
#pragma unroll
    for (int r = 1; r <= R; ++r) {
        float best = INFINITY;
#pragma unroll
        for (int j = 0; j <= R; ++j) {
            if (j <= r) {
                float av = (j >= 1) ? ((j <= LA) ? a[j - 1] : INFINITY) : -INFINITY;
                float bv = (r - j >= 1) ? ((r - j <= LB) ? b[r - j - 1] : INFINITY) : -INFINITY;
                best = fminf(best, fmaxf(av, bv));
            }
        }
        out[r - 1] = best;
    }
}

// ---------------- K1b: tau + mode from truncated per-chunk lists ----------------
// Exactness: if every chunk's kept-last > tau, every candidate with d <= tau is in
// the lists -> tau, cnt_lt, cnt_eq all exact. Encoding of budgetbuf:
//   0  -> surplus==0: accepting ALL d<=tau (ascending m) is exactly the stable top-20
//   >0 -> exact tie budget (rank ties, ascending m)            [measure-zero case]
//   -1 -> truncation flag tripped: exact serial fallback       [P ~ 1e-6 * NQ per run]
template <int NCH, int SLOTS>
__global__ __launch_bounds__(256) void knn_tau(const float* __restrict__ pd,
                                               float* __restrict__ taubuf,
                                               int* __restrict__ budgetbuf) {
    const int q = blockIdx.x * 256 + threadIdx.x;   // 128 blocks
    constexpr int CH = NN / NCH;
    constexpr int LEN = SLOTS - 1;                  // effective list length (self dropped)
    const int ch_self = (q & (NN - 1)) / CH;

    float L[NCH][LEN];
#pragma unroll
    for (int c = 0; c < NCH; ++c) {
        float raw[SLOTS];
#pragma unroll
        for (int j = 0; j < SLOTS; ++j) raw[j] = pd[(size_t)(c * SLOTS + j) * NQ + q];
        bool shift = (c == ch_self);   // drop self's exact-0 at slot 0
#pragma unroll
        for (int j = 0; j < LEN; ++j) L[c][j] = shift ? raw[j + 1] : raw[j];
    }

    // sequential merge: T = top-20 of union of the NCH truncated lists
    float T[KK];
    mergeR<LEN, LEN, KK>(L[0], L[1], T);
#pragma unroll
    for (int c = 2; c < NCH; ++c) {
        float M[KK];
        mergeR<KK, LEN, KK>(T, L[c], M);
#pragma unroll
        for (int j = 0; j < KK; ++j) T[j] = M[j];
    }

    float tau = T[KK - 1];
    int cnt_lt = 0, cnt_eq = 0;
    bool flag = false;
#pragma unroll
    for (int c = 0; c < NCH; ++c) {
#pragma unroll
        for (int j = 0; j < LEN; ++j) {
            cnt_lt += (L[c][j] < tau) ? 1 : 0;
            cnt_eq += (L[c][j] == tau) ? 1 : 0;
        }
        flag = flag || (L[c][LEN - 1] <= tau);
    }
    int surplus = cnt_lt + cnt_eq - KK;             // >=0 when flag==0
    taubuf[q] = tau;
    budgetbuf[q] = flag ? -1 : (surplus == 0 ? 0 : (KK - cnt_lt));
}

// ---------------- K1c: collect ----------------
__device__ __forceinline__ int prefix_count(unsigned long long mask) {
    int r = __builtin_amdgcn_mbcnt_lo((unsigned)mask, 0);
    return __builtin_amdgcn_mbcnt_hi((unsigned)(mask >> 32), r);
}

// single-query exact collect: handles budget==0 / >0 / -1
__device__ void collect_one(const float4* __restrict__ pb, int n, float qx, float qy,
                            float qz, float sqn, float tau, int budget, int lane,
                            int* __restrict__ erow) {
    if (budget == 0) {
        int cnt = 0;
        for (int it = 0; it < 64; ++it) {
            int m = it * 64 + lane;
            float4 p = pb[m];
            float d = np_dist(qx, qy, qz, sqn, p);
            bool acc = (d <= tau) && (m != n);
            unsigned long long macc = __ballot(acc);
            if (macc) {
                int pos = cnt + prefix_count(macc);
                if (acc) erow[pos] = m;
                cnt += __popcll(macc);
            }
        }
    } else if (budget > 0) {
        int cnt = 0, ties = 0;
        for (int it = 0; it < 64; ++it) {
            int m = it * 64 + lane;
            float4 p = pb[m];
            float d = np_dist(qx, qy, qz, sqn, p);
            bool valid = (m != n);
            bool is_lt = valid && (d < tau);
            bool is_tie = valid && (d == tau);
            unsigned long long mtie = __ballot(is_tie);
            int tie_rank = ties + prefix_count(mtie);
            bool acc = is_lt || (is_tie && tie_rank < budget);
            unsigned long long macc = __ballot(acc);
            int pos = cnt + prefix_count(macc);
            if (acc && pos < KK) erow[pos] = m;
            cnt += __popcll(macc);
            ties += __popcll(mtie);
        }
        if (lane == 0) {
            for (int j = cnt; j < KK; ++j) erow[j] = (n + 1 + j) & (NN - 1);  // unreachable guard
        }
    } else if (lane == 0) {
        // exact serial fallback: stable top-20 by (d, m) u64 keys — truncation tripped
        unsigned long long bk[KK];
#pragma unroll
        for (int j = 0; j < KK; ++j) bk[j] = ~0ULL;
        for (int m = 0; m < NN; ++m) {
            if (m == n) continue;
            float d = np_dist(qx, qy, qz, sqn, pb[m]);
            unsigned u = __float_as_uint(d);
            u ^= (unsigned)((int)u >> 31) | 0x80000000u;        // order-preserving map
            unsigned long long key = ((unsigned long long)u << 32) | (unsigned)m;
            if (key < bk[KK - 1]) {
#pragma unroll
                for (int s = KK - 1; s >= 1; --s) {
                    bool sh = bk[s - 1] > key;
                    bool here = bk[s] > key;
                    bk[s] = sh ? bk[s - 1] : (here ? key : bk[s]);
                }
                if (bk[0] > key) bk[0] = key;
            }
        }
        for (int j = 0; j < KK; ++j) erow[j] = (int)(bk[j] & 0xFFFFFFFFu);
    }
}

// 8 queries per wave: one candidate load feeds 8 distance tests (L2 traffic /8).
// 1024 blocks x 256 threads; wave w handles queries (blockIdx*4+w)*8 .. +7 (same batch).
__global__ __launch_bounds__(256) void knn_collect(const float4* __restrict__ pts4,
                                                   const float* __restrict__ taubuf,
                                                   const int* __restrict__ budgetbuf,
                                                   int* __restrict__ edges) {
    const int wave = threadIdx.x >> 6;
    const int lane = threadIdx.x & 63;
    const int q0 = (blockIdx.x * 4 + wave) * 8;
    const int b = q0 >> 12;                          // 8 | 4096 -> same batch for all 8
    const float4* pb = pts4 + (size_t)b * NN;

    int nj[8], bj[8];
    float qxj[8], qyj[8], qzj[8], sqj[8], tj[8];
    int orb = 0;
#pragma unroll
    for (int j = 0; j < 8; ++j) {
        int q = q0 + j;
        nj[j] = q & (NN - 1);
        float4 me = pb[nj[j]];                       // uniform -> broadcast
        qxj[j] = me.x; qyj[j] = me.y; qzj[j] = me.z; sqj[j] = me.w;
        tj[j] = taubuf[q];
        bj[j] = budgetbuf[q];
        orb |= bj[j];
    }

    if (orb == 0) {                                  // wave-uniform fast gate
        int cnt[8] = {0, 0, 0, 0, 0, 0, 0, 0};
        for (int it = 0; it < 64; ++it) {
            int m = it * 64 + lane;
            float4 p = pb[m];                        // one coalesced b128 for 8 queries
#pragma unroll
            for (int j = 0; j < 8; ++j) {
                float d = np_dist(qxj[j], qyj[j], qzj[j], sqj[j], p);
                bool acc = (d <= tj[j]) && (m != nj[j]);
                unsigned long long mk = __ballot(acc);
                if (mk) {
                    int pos = cnt[j] + prefix_count(mk);
                    if (acc) edges[(size_t)(q0 + j) * KK + pos] = m;
                    cnt[j] += __popcll(mk);
                }
            }
        }
    } else {
        // rare: at least one query needs tie/fallback handling — do all 8 exactly
#pragma unroll
        for (int j = 0; j < 8; ++j) {
            collect_one(pb, nj[j], qxj[j], qyj[j], qzj[j], sqj[j], tj[j], bj[j], lane,
                        edges + (size_t)(q0 + j) * KK);
        }
    }
}

// ---------------- K2: projections P1 = (W1-W2)·x_n, P2 = W2·x_n ----------------
__global__ __launch_bounds__(256) void proj_kernel(const float* __restrict__ x,
                                                   const float* __restrict__ W,
                                                   float* __restrict__ P1,
                                                   float* __restrict__ P2) {
    const int wid = blockIdx.x * 4 + (threadIdx.x >> 6);  // 8192 = 512 row-blocks x 16 o-groups
    const int lane = threadIdx.x & 63;
    const int row_block = wid >> 4;
    const int og = __builtin_amdgcn_readfirstlane(wid & 15);
    const int row = row_block * 64 + lane;
    const int b = row >> 12;
    const int n = row & (NN - 1);
    const float* xb = x + (size_t)b * CC * NN;

    float p1[4] = {0.f, 0.f, 0.f, 0.f};
    float p2[4] = {0.f, 0.f, 0.f, 0.f};
#pragma unroll 8
    for (int c = 0; c < CC; ++c) {
        float xv = xb[(size_t)c * NN + n];                 // coalesced 256B
#pragma unroll
        for (int j = 0; j < 4; ++j) {
            int o = og * 4 + j;
            float w1 = W[o * 2 * CC + c];                  // scalar (s_load) — uniform
            float w2 = W[o * 2 * CC + CC + c];
            p1[j] += (w1 - w2) * xv;
            p2[j] += w2 * xv;
        }
    }
#pragma unroll
    for (int j = 0; j < 4; ++j) {
        int o = og * 4 + j;
        P1[(size_t)row * 64 + o] = p1[j];
        P2[(size_t)row * 64 + o] = p2[j];
    }
}

// ---------------- K3a: BN partial sums + per-row hmax -> transposed store into d_out --------
// XCD-batch swizzle: batch = blockIdx & 7, so (under bid%8 XCD round-robin) each XCD
// gathers within ONE batch's P2 (1 MB -> L2-resident). partials stay indexed by
// row-block id (= b*64+inner), so finalize's summation order — and every output
// bit — is unchanged vs the unswizzled mapping.
__global__ __launch_bounds__(256) void stats_kernel(const float* __restrict__ P1,
                                                    const float* __restrict__ P2,
                                                    const int* __restrict__ edges,
                                                    float* __restrict__ partials,
                                                    float* __restrict__ out) {
    int blk = blockIdx.x;          // 512 blocks, 64 rows each
    int b = blk & 7;               // batch
    int inner = blk >> 3;          // 0..63
    int row0 = b * NN + inner * 64;
    int pblk = row0 >> 6;          // row-block id for partials (order-preserving)
    int o = threadIdx.x & 63;
    int rq = threadIdx.x >> 6;
    int n0 = row0 & (NN - 1);
    const float* P2b = P2 + (size_t)b * NN * 64;
    __shared__ float tile[64][65];
    float s = 0.f, s2 = 0.f;
    for (int rr = rq; rr < 64; rr += 4) {
        int row = row0 + rr;
        float p1 = P1[row * 64 + o];
        const int* e = edges + row * KK;
        float hm = -INFINITY;
#pragma unroll
        for (int j = 0; j < KK; ++j) {
            int ej = e[j];                      // wave-uniform
            float v = p1 + P2b[ej * 64 + o];    // coalesced 256B gather (L2-resident)
            s += v;
            s2 += v * v;
            hm = fmaxf(hm, v);
        }
        tile[rr][o] = hm;
    }
    __shared__ float sh1[256], sh2[256];
    sh1[threadIdx.x] = s;
    sh2[threadIdx.x] = s2;
    __syncthreads();
    if (threadIdx.x < 64) {
        float a = sh1[threadIdx.x] + sh1[threadIdx.x + 64] + sh1[threadIdx.x + 128] + sh1[threadIdx.x + 192];
        float a2 = sh2[threadIdx.x] + sh2[threadIdx.x + 64] + sh2[threadIdx.x + 128] + sh2[threadIdx.x + 192];
        partials[pblk * 128 + threadIdx.x] = a;
        partials[pblk * 128 + 64 + threadIdx.x] = a2;
    }
    int w2 = threadIdx.x >> 6;
    int lane = threadIdx.x & 63;
    for (int o2 = w2 * 16; o2 < w2 * 16 + 16; ++o2) {
        out[((size_t)(b * 64 + o2)) * NN + n0 + lane] = tile[lane][o2];  // coalesced 256B
    }
}

// ---------------- K3b: finalize BN -> A,C consts ----------------
__global__ __launch_bounds__(128) void finalize_kernel(const float* __restrict__ partials,
                                                       const float* __restrict__ gamma,
                                                       const float* __restrict__ beta,
                                                       float* __restrict__ consts) {
    int t = threadIdx.x;   // 0..127
    float s = 0.f;
    for (int i = 0; i < 512; ++i) s += partials[i * 128 + t];
    __shared__ float sh[128];
    sh[t] = s;
    __syncthreads();
    if (t < 64) {
        float sum = sh[t];
        float sumsq = sh[64 + t];
        const float M = (float)((size_t)BB * NN * KK);  // 655360
        float mean = sum / M;
        float var = sumsq / M - mean * mean;
        float inv = 1.0f / sqrtf(var + 1e-5f);
        float A = gamma[t] * inv;
        float Cv = beta[t] - mean * A;
        consts[t] = A;
        consts[64 + t] = Cv;
    }
}

// ---------------- K4: elementwise act over hmax (monotone: max act == act(max h) for A>=0) ----------
__global__ __launch_bounds__(256) void out2_kernel(const float* __restrict__ P1,
                                                   const float* __restrict__ P2,
                                                   const int* __restrict__ edges,
                                                   const float* __restrict__ consts,
                                                   float* __restrict__ out) {
    const int blk = blockIdx.x;        // 512 = b*64 + o
    const int b = blk >> 6;
    const int o = blk & 63;
    const float A = consts[o];
    const float Cv = consts[64 + o];
    float* orow = out + (size_t)blk * NN;   // out[b][o][:]
    if (A >= 0.f) {
#pragma unroll
        for (int it = 0; it < 4; ++it) {
            int idx = (it * 256 + threadIdx.x) * 4;
            float4 v = *(const float4*)(orow + idx);
            float h0 = v.x * A + Cv, h1 = v.y * A + Cv, h2 = v.z * A + Cv, h3 = v.w * A + Cv;
            v.x = h0 >= 0.f ? h0 : 0.2f * h0;
            v.y = h1 >= 0.f ? h1 : 0.2f * h1;
            v.z = h2 >= 0.f ? h2 : 0.2f * h2;
            v.w = h3 >= 0.f ? h3 : 0.2f * h3;
            *(float4*)(orow + idx) = v;
        }
    } else {
        // exact fallback (A<0 flips monotonicity) — never taken for this data
        const float* P2b = P2 + (size_t)b * NN * 64;
        for (int n = threadIdx.x; n < NN; n += 256) {
            size_t row = (size_t)b * NN + n;
            float p1 = P1[row * 64 + o];
            const int* e = edges + row * KK;
            float mx = -INFINITY;
            for (int j = 0; j < KK; ++j) {
                float h = p1 + P2b[e[j] * 64 + o];
                float hn = h * A + Cv;
                mx = fmaxf(mx, hn >= 0.f ? hn : 0.2f * hn);
            }
            orow[n] = mx;
        }
    }
}

extern "C" void kernel_launch(void* const* d_in, const int* in_sizes, int n_in,
                              void* d_out, int out_size, void* d_ws, size_t ws_size,
                              hipStream_t stream) {
    const float* x = (const float*)d_in[0];
    const float* W = (const float*)d_in[1];
    const float* gamma = (const float*)d_in[2];
    const float* beta = (const float*)d_in[3];
    float* out = (float*)d_out;

    // De-aliased layout: only pd shares memory (with P1/P2, dead before proj writes).
    char* w = (char*)d_ws;
    float4* pts4      = (float4*)(w + 0);                 //   524288 B
    float*  taubuf    = (float*)(w + 524288);             //   131072 B
    int*    budgetbuf = (int*)(w + 655360);               //   131072 B
    float*  partials  = (float*)(w + 786432);             //   262144 B
    float*  consts    = (float*)(w + 1048576);            //      512 B (pad to 1024)
    int*    edges     = (int*)(w + 1049600);              //  2621440 B
    char*   region    = w + 3671040;
    float*  P1 = (float*)region;                          //  8388608 B
    float*  P2 = P1 + (size_t)NQ * 64;                    //  8388608 B
    float*  pd = (float*)region;                          // aliases P1/P2 head

    const size_t need16 = 3671040 + (size_t)16 * 11 * NQ * 4;   // 26,739,712 B

    prep_kernel<<<128, 256, 0, stream>>>(x, pts4);
    if (ws_size >= need16) {
        knn_part<16, 11><<<128 * 16, 256, 0, stream>>>(pts4, pd);
        knn_tau<16, 11><<<128, 256, 0, stream>>>(pd, taubuf, budgetbuf);
    } else {
        knn_part<8, 13><<<128 * 8, 256, 0, stream>>>(pts4, pd);
        knn_tau<8, 13><<<128, 256, 0, stream>>>(pd, taubuf, budgetbuf);
    }
    knn_collect<<<1024, 256, 0, stream>>>(pts4, taubuf, budgetbuf, edges);

    proj_kernel<<<2048, 256, 0, stream>>>(x, W, P1, P2);
    stats_kernel<<<512, 256, 0, stream>>>(P1, P2, edges, partials, out);
    finalize_kernel<<<1, 128, 0, stream>>>(partials, gamma, beta, consts);
    out2_kernel<<<512, 256, 0, stream>>>(P1, P2, edges, consts, out);
}